// Round 4
// baseline (757.189 us; speedup 1.0000x reference)
//
#include <hip/hip_runtime.h>
#include <hip/hip_bf16.h>

#define NN 50000
#define EE 640000
#define DD 128
#define GG 64
#define STEPS 4
#define XP 32

static inline int cdiv(int a, int b) { return (a + b - 1) / b; }

typedef __attribute__((ext_vector_type(8))) short bf16x8;
typedef __attribute__((ext_vector_type(4))) float f32x4;

__device__ __forceinline__ float lk(float z) { return z >= 0.f ? z : 0.01f * z; }
__device__ __forceinline__ float b2f(short b) { return __uint_as_float(((unsigned)(unsigned short)b) << 16); }
__device__ __forceinline__ unsigned short f2b(float f) {
    unsigned u = __float_as_uint(f);
    return (unsigned short)((u + 0x7FFFu + ((u >> 16) & 1u)) >> 16);   // RNE
}

// ---------------- fp32 -> bf16 conversion (vec4) ----------------
__global__ void k_f2b(const float* __restrict__ in, unsigned short* __restrict__ out, int n4) {
    int i = blockIdx.x * blockDim.x + threadIdx.x;
    if (i < n4) {
        float4 v = reinterpret_cast<const float4*>(in)[i];
        ushort4 o;
        o.x = f2b(v.x); o.y = f2b(v.y); o.z = f2b(v.z); o.w = f2b(v.w);
        reinterpret_cast<ushort4*>(out)[i] = o;
    }
}

// ---------------- CSR build ----------------
__global__ void k_count(const int* __restrict__ dst, int* __restrict__ deg) {
    int e = blockIdx.x * blockDim.x + threadIdx.x;
    if (e < EE) atomicAdd(&deg[dst[e]], 1);
}

__global__ void k_scan(const int* __restrict__ deg, int* __restrict__ off, int* __restrict__ cursor) {
    __shared__ int wsum[16];
    __shared__ int sbase;
    int tid = threadIdx.x;
    int lane = tid & 63, wv = tid >> 6;
    if (tid == 0) sbase = 0;
    __syncthreads();
    for (int c0 = 0; c0 < NN; c0 += 1024) {
        int i = c0 + tid;
        int v = (i < NN) ? deg[i] : 0;
        int x = v;
        #pragma unroll
        for (int o = 1; o < 64; o <<= 1) { int t = __shfl_up(x, o); if (lane >= o) x += t; }
        if (lane == 63) wsum[wv] = x;
        __syncthreads();
        if (wv == 0 && lane < 16) {
            int wx = wsum[lane];
            #pragma unroll
            for (int o = 1; o < 16; o <<= 1) { int t = __shfl_up(wx, o); if (lane >= o) wx += t; }
            wsum[lane] = wx;
        }
        __syncthreads();
        int wbase = (wv == 0) ? 0 : wsum[wv - 1];
        int excl = sbase + wbase + x - v;
        if (i < NN) { off[i] = excl; cursor[i] = excl; }
        int tot = wsum[15];
        __syncthreads();
        if (tid == 0) sbase += tot;
        __syncthreads();
    }
    if (tid == 0) off[NN] = sbase;
}

__global__ void k_fill(const int* __restrict__ src, const int* __restrict__ dst,
                       int* __restrict__ cursor, int* __restrict__ csr) {
    int e = blockIdx.x * blockDim.x + threadIdx.x;
    if (e < EE) {
        int d = dst[e];
        int p = atomicAdd(&cursor[d], 1);
        csr[p] = src[e];
    }
}

__global__ void k_goff(const int* __restrict__ batch, int* __restrict__ goff) {
    int i = blockIdx.x * blockDim.x + threadIdx.x;
    if (i >= NN) return;
    int b = batch[i];
    int prev = (i == 0) ? -1 : batch[i - 1];
    for (int g = prev + 1; g <= b; ++g) goff[g] = i;
    if (i == NN - 1) for (int g = b + 1; g <= GG; ++g) goff[g] = NN;
}

// ---------------- MFMA GEMM: Y = leaky(X @ W^T + b) [+ resid] ----------------
// X1b [N,128] bf16 (+ X2b [N,128] bf16 if TWO_IN -> K=256), Wb [128,KDIM] bf16 row-major.
// Always writes Yb (bf16). If RESID: v = leaky(acc+bias) + resid_f32, writes Yf (f32) too.
// Block: 256 thr = 4 waves; block tile 64 rows x 128 cols; wave w: rows w*16..w*16+15.
// MFMA 16x16x32: A row = lane&15, k = kc*32 + (lane>>4)*8 + j (contiguous 16B load);
// B col = lane&15 (W row o), same k mapping. D: col = lane&15, row = (lane>>4)*4 + reg.
template<int KDIM, bool TWO_IN, bool RESID>
__global__ __launch_bounds__(256) void k_mfma(
    const unsigned short* __restrict__ X1b, const unsigned short* __restrict__ X2b,
    const unsigned short* __restrict__ Wb, const float* __restrict__ bias,
    unsigned short* __restrict__ Yb, float* __restrict__ Yf, const float* __restrict__ resid)
{
    const int tid = threadIdx.x;
    const int wv = tid >> 6, lane = tid & 63;
    const int lo = lane & 15, hi = lane >> 4;
    const int n0 = blockIdx.x * 64;
    const int arow = n0 + wv * 16 + lo;
    const bool rvalid = arow < NN;

    f32x4 acc[8];
    #pragma unroll
    for (int t = 0; t < 8; ++t) acc[t] = (f32x4){0.f, 0.f, 0.f, 0.f};

    constexpr int KCH = KDIM / 32;
    #pragma unroll
    for (int kc = 0; kc < KCH; ++kc) {
        const int k = kc * 32 + hi * 8;
        bf16x8 a = (bf16x8)(short)0;
        if (rvalid) {
            if (TWO_IN) {
                const unsigned short* base = (k < 128) ? &X1b[(size_t)arow * 128 + k]
                                                       : &X2b[(size_t)arow * 128 + (k - 128)];
                a = *reinterpret_cast<const bf16x8*>(base);
            } else {
                a = *reinterpret_cast<const bf16x8*>(&X1b[(size_t)arow * KDIM + k]);
            }
        }
        #pragma unroll
        for (int t = 0; t < 8; ++t) {
            const int o = t * 16 + lo;
            bf16x8 b = *reinterpret_cast<const bf16x8*>(&Wb[(size_t)o * KDIM + k]);
            acc[t] = __builtin_amdgcn_mfma_f32_16x16x32_bf16(a, b, acc[t], 0, 0, 0);
        }
    }

    const int orow = n0 + wv * 16 + hi * 4;
    #pragma unroll
    for (int t = 0; t < 8; ++t) {
        const int col = t * 16 + lo;
        const float bc = bias[col];
        #pragma unroll
        for (int r = 0; r < 4; ++r) {
            const int n = orow + r;
            if (n < NN) {
                float v = lk(acc[t][r] + bc);
                if (RESID) {
                    v += resid[(size_t)n * 128 + col];
                    Yf[(size_t)n * 128 + col] = v;
                }
                Yb[(size_t)n * 128 + col] = f2b(v);
            }
        }
    }
}

// ---------------- scatter-max via CSR: one wave per node, 4 edges/iter, bf16 ----------------
__global__ __launch_bounds__(256) void k_aggmax(const unsigned short* __restrict__ yb,
                                                const int* __restrict__ off,
                                                const int* __restrict__ csr,
                                                unsigned short* __restrict__ aggb) {
    int gtid = blockIdx.x * blockDim.x + threadIdx.x;
    int node = gtid >> 6;
    if (node >= NN) return;
    int lane = threadIdx.x & 63;
    int slot = lane >> 4, c8 = (lane & 15) * 8;
    int b = off[node], e = off[node + 1];
    int deg = e - b;
    float m[8];
    #pragma unroll
    for (int j = 0; j < 8; ++j) m[j] = -3.4e38f;
    if (deg > 0) {
        int T = (deg + 3) >> 2;
        for (int it = 0; it < T; ++it) {
            int p = b + it * 4 + slot;
            int idx = csr[p < e ? p : b];
            bf16x8 v = *reinterpret_cast<const bf16x8*>(&yb[(size_t)idx * 128 + c8]);
            #pragma unroll
            for (int j = 0; j < 8; ++j) m[j] = fmaxf(m[j], b2f(v[j]));
        }
    }
    #pragma unroll
    for (int j = 0; j < 8; ++j) m[j] = fmaxf(m[j], __shfl_xor(m[j], 16));
    #pragma unroll
    for (int j = 0; j < 8; ++j) m[j] = fmaxf(m[j], __shfl_xor(m[j], 32));
    if (slot == 0) {
        bf16x8 o;
        #pragma unroll
        for (int j = 0; j < 8; ++j) o[j] = (deg > 0) ? (short)f2b(m[j]) : (short)0;
        *reinterpret_cast<bf16x8*>(&aggb[(size_t)node * 128 + c8]) = o;
    }
}

// ---------------- gate: 32 lanes per node, bf16 ----------------
__global__ __launch_bounds__(256) void k_gate(const unsigned short* __restrict__ xb,
                                              const unsigned short* __restrict__ wgb,
                                              const float* __restrict__ bg, float* __restrict__ gate) {
    int gtid = blockIdx.x * blockDim.x + threadIdx.x;
    int node = gtid >> 5;
    if (node >= NN) return;
    int l = threadIdx.x & 31;
    ushort4 xv = *reinterpret_cast<const ushort4*>(&xb[(size_t)node * 128 + l * 4]);
    ushort4 wv = *reinterpret_cast<const ushort4*>(&wgb[l * 4]);
    float s = b2f(xv.x) * b2f(wv.x) + b2f(xv.y) * b2f(wv.y) +
              b2f(xv.z) * b2f(wv.z) + b2f(xv.w) * b2f(wv.w);
    #pragma unroll
    for (int o = 16; o > 0; o >>= 1) s += __shfl_xor(s, o);
    if (l == 0) gate[node] = s + bg[0];
}

// ---------------- per-graph softmax stats (deterministic) ----------------
__global__ __launch_bounds__(256) void k_gstats(const float* __restrict__ gate, const int* __restrict__ goff,
                                                float* __restrict__ efac, float* __restrict__ invden) {
    __shared__ float red[256];
    int g = blockIdx.x;
    int tid = threadIdx.x;
    int b = goff[g], e = goff[g + 1];
    float m = -3.4e38f;
    for (int i = b + tid; i < e; i += 256) m = fmaxf(m, gate[i]);
    red[tid] = m; __syncthreads();
    for (int o = 128; o > 0; o >>= 1) { if (tid < o) red[tid] = fmaxf(red[tid], red[tid + o]); __syncthreads(); }
    float gm = red[0];
    __syncthreads();
    float s = 0.f;
    for (int i = b + tid; i < e; i += 256) { float ev = __expf(gate[i] - gm); efac[i] = ev; s += ev; }
    red[tid] = s; __syncthreads();
    for (int o = 128; o > 0; o >>= 1) { if (tid < o) red[tid] += red[tid + o]; __syncthreads(); }
    if (tid == 0) { float d = red[0]; if (d == 0.f) d = 1.f; invden[g] = 1.f / d; }
}

// ---------------- xg partial sums (deterministic order), bf16 feat ----------------
__global__ __launch_bounds__(128) void k_xgpart(const float* __restrict__ efac,
                                                const unsigned short* __restrict__ featb,
                                                const int* __restrict__ goff, float* __restrict__ part) {
    int g = blockIdx.x >> 5, p = blockIdx.x & 31;
    int d = threadIdx.x;
    int b = goff[g], e = goff[g + 1];
    int len = e - b;
    int chunk = (len + XP - 1) / XP;
    int s0 = b + p * chunk;
    int s1 = min(e, s0 + chunk);
    float acc = 0.f;
    #pragma unroll 2
    for (int i = s0; i < s1; ++i) acc += efac[i] * b2f(featb[(size_t)i * 128 + d]);
    part[((size_t)g * XP + p) * 128 + d] = acc;
}

// ---------------- global transform ----------------
__global__ __launch_bounds__(128) void k_gtrans(const float* __restrict__ part, const float* __restrict__ invden,
                                                const float* __restrict__ Wt, const float* __restrict__ bt,
                                                float* __restrict__ xglob) {
    __shared__ float cat[256];
    int g = blockIdx.x;
    int o = threadIdx.x;
    float xgv = 0.f;
    #pragma unroll
    for (int p = 0; p < XP; ++p) xgv += part[((size_t)g * XP + p) * 128 + o];
    cat[o] = xgv * invden[g];
    cat[128 + o] = xglob[(size_t)g * 128 + o];
    __syncthreads();
    float accv = bt[o];
    const float4* w4 = reinterpret_cast<const float4*>(&Wt[(size_t)o * 256]);
    #pragma unroll 8
    for (int k4 = 0; k4 < 64; ++k4) {
        float4 wv = w4[k4];
        accv += cat[4 * k4 + 0] * wv.x + cat[4 * k4 + 1] * wv.y + cat[4 * k4 + 2] * wv.z + cat[4 * k4 + 3] * wv.w;
    }
    float outv = lk(accv) + cat[128 + o];
    xglob[(size_t)g * 128 + o] = outv;
}

extern "C" void kernel_launch(void* const* d_in, const int* in_sizes, int n_in,
                              void* d_out, int out_size, void* d_ws, size_t ws_size,
                              hipStream_t stream) {
    const float* x_in  = (const float*)d_in[0];
    const float* xg_in = (const float*)d_in[1];
    const float* Wm = (const float*)d_in[3];
    const float* bm = (const float*)d_in[4];
    const float* Wa = (const float*)d_in[5];
    const float* ba = (const float*)d_in[6];
    const float* Wg = (const float*)d_in[7];
    const float* bg = (const float*)d_in[8];
    const float* Wf = (const float*)d_in[9];
    const float* bf = (const float*)d_in[10];
    const float* Wt = (const float*)d_in[11];
    const float* bt = (const float*)d_in[12];
    const int* eidx  = (const int*)d_in[13];
    const int* batch = (const int*)d_in[14];

    float* xout  = (float*)d_out;                 // [N,128] evolving x (f32 carry)
    float* xglob = xout + (size_t)NN * DD;        // [G,128] evolving x_global

    char* w = (char*)d_ws;
    unsigned short* yb   = (unsigned short*)w; w += (size_t)NN * DD * 2;  // msg / feat bf16
    unsigned short* aggb = (unsigned short*)w; w += (size_t)NN * DD * 2;
    unsigned short* xb   = (unsigned short*)w; w += (size_t)NN * DD * 2;  // bf16 shadow of x
    unsigned short* Wm_b = (unsigned short*)w; w += (size_t)STEPS * DD * DD * 2;
    unsigned short* Wa_b = (unsigned short*)w; w += (size_t)STEPS * DD * 2 * DD * 2;
    unsigned short* Wf_b = (unsigned short*)w; w += (size_t)STEPS * DD * DD * 2;
    unsigned short* Wg_b = (unsigned short*)w; w += (size_t)STEPS * DD * 2;
    float* gate   = (float*)w; w += (size_t)NN * 4;
    float* efac   = (float*)w; w += (size_t)NN * 4;
    float* part   = (float*)w; w += (size_t)GG * XP * DD * 4;
    float* invden = (float*)w; w += (size_t)GG * 4;
    int* deg    = (int*)w; w += (size_t)(NN + 1) * 4;
    int* off    = (int*)w; w += (size_t)(NN + 1) * 4;
    int* cursor = (int*)w; w += (size_t)NN * 4;
    int* csr    = (int*)w; w += (size_t)EE * 4;
    int* goff   = (int*)w; w += (size_t)(GG + 1) * 4;

    const int* srcI = eidx;
    const int* dstI = eidx + EE;

    hipMemcpyAsync(xout,  x_in,  (size_t)NN * DD * 4, hipMemcpyDeviceToDevice, stream);
    hipMemcpyAsync(xglob, xg_in, (size_t)GG * DD * 4, hipMemcpyDeviceToDevice, stream);

    // one-time conversions
    k_f2b<<<cdiv(NN * DD / 4, 256), 256, 0, stream>>>(x_in, xb, NN * DD / 4);
    k_f2b<<<cdiv(STEPS * DD * DD / 4, 256), 256, 0, stream>>>(Wm, Wm_b, STEPS * DD * DD / 4);
    k_f2b<<<cdiv(STEPS * DD * 2 * DD / 4, 256), 256, 0, stream>>>(Wa, Wa_b, STEPS * DD * 2 * DD / 4);
    k_f2b<<<cdiv(STEPS * DD * DD / 4, 256), 256, 0, stream>>>(Wf, Wf_b, STEPS * DD * DD / 4);
    k_f2b<<<1, 256, 0, stream>>>(Wg, Wg_b, STEPS * DD / 4);

    // CSR by dst (once per call; reused across steps)
    hipMemsetAsync(deg, 0, (size_t)NN * 4, stream);
    k_count<<<cdiv(EE, 256), 256, 0, stream>>>(dstI, deg);
    k_scan<<<1, 1024, 0, stream>>>(deg, off, cursor);
    k_fill<<<cdiv(EE, 256), 256, 0, stream>>>(srcI, dstI, cursor, csr);
    k_goff<<<cdiv(NN, 256), 256, 0, stream>>>(batch, goff);

    const int gemmGrid = cdiv(NN, 64);            // 782
    const int aggGrid  = cdiv(NN * 64, 256);      // 12500
    const int gateGrid = cdiv(NN * 32, 256);      // 6250

    for (int i = 0; i < STEPS; ++i) {
        const unsigned short* Wmi = Wm_b + (size_t)i * DD * DD;
        const float* bmi = bm + (size_t)i * DD;
        const unsigned short* Wai = Wa_b + (size_t)i * DD * 2 * DD;
        const float* bai = ba + (size_t)i * DD;
        const unsigned short* Wgi = Wg_b + (size_t)i * DD;
        const float* bgi = bg + (size_t)i;
        const unsigned short* Wfi = Wf_b + (size_t)i * DD * DD;
        const float* bfi = bf + (size_t)i * DD;
        const float* Wti = Wt + (size_t)i * DD * 2 * DD;
        const float* bti = bt + (size_t)i * DD;

        // yb = bf16(leaky(x @ Wm^T + bm))
        k_mfma<128, false, false><<<gemmGrid, 256, 0, stream>>>(xb, nullptr, Wmi, bmi, yb, nullptr, nullptr);
        // aggb[n] = max over in-edges of yb[src] (exact in bf16)
        k_aggmax<<<aggGrid, 256, 0, stream>>>(yb, off, csr, aggb);
        // x = leaky([x, agg] @ Wa^T + ba) + x ; writes f32 xout and bf16 xb
        k_mfma<256, true, true><<<gemmGrid, 256, 0, stream>>>(xb, aggb, Wai, bai, xb, xout, xout);
        // gate = x . wg + bg
        k_gate<<<gateGrid, 256, 0, stream>>>(xb, Wgi, bgi, gate);
        // feat = bf16(leaky(x @ Wf^T + bf))  (reuse yb)
        k_mfma<128, false, false><<<gemmGrid, 256, 0, stream>>>(xb, nullptr, Wfi, bfi, yb, nullptr, nullptr);
        // per-graph softmax stats
        k_gstats<<<GG, 256, 0, stream>>>(gate, goff, efac, invden);
        // xg partials and global transform
        k_xgpart<<<GG * XP, 128, 0, stream>>>(efac, yb, goff, part);
        k_gtrans<<<GG, 128, 0, stream>>>(part, invden, Wti, bti, xglob);
    }
}

// Round 8
// 664.316 us; speedup vs baseline: 1.1398x; 1.1398x over previous
//
#include <hip/hip_runtime.h>
#include <hip/hip_bf16.h>

#define NN 50000
#define EE 640000
#define DD 128
#define GG 64
#define STEPS 4
#define XP 32
#define NB 196   // cdiv(NN,256) scan blocks

static inline int cdiv(int a, int b) { return (a + b - 1) / b; }

typedef __attribute__((ext_vector_type(8))) short bf16x8;
typedef __attribute__((ext_vector_type(4))) float f32x4;

__device__ __forceinline__ float lk(float z) { return z >= 0.f ? z : 0.01f * z; }
__device__ __forceinline__ float b2f(short b) { return __uint_as_float(((unsigned)(unsigned short)b) << 16); }
__device__ __forceinline__ unsigned short f2b(float f) {
    unsigned u = __float_as_uint(f);
    return (unsigned short)((u + 0x7FFFu + ((u >> 16) & 1u)) >> 16);   // RNE
}

// ---------------- fp32 -> bf16 conversion (vec4) ----------------
__global__ void k_f2b(const float* __restrict__ in, unsigned short* __restrict__ out, int n4) {
    int i = blockIdx.x * blockDim.x + threadIdx.x;
    if (i < n4) {
        float4 v = reinterpret_cast<const float4*>(in)[i];
        ushort4 o;
        o.x = f2b(v.x); o.y = f2b(v.y); o.z = f2b(v.z); o.w = f2b(v.w);
        reinterpret_cast<ushort4*>(out)[i] = o;
    }
}

// fused weight conversion: Wm | Wa | Wf segments (vec4 units)
#define WC1 (STEPS * DD * DD / 4)
#define WC2 (STEPS * DD * 2 * DD / 4)
#define WC3 (STEPS * DD * DD / 4)
__global__ void k_wcvt(const float* __restrict__ Wm, const float* __restrict__ Wa, const float* __restrict__ Wf,
                       unsigned short* __restrict__ Wm_b, unsigned short* __restrict__ Wa_b,
                       unsigned short* __restrict__ Wf_b) {
    int i = blockIdx.x * blockDim.x + threadIdx.x;
    const float* src; unsigned short* dst; int j = i;
    if (j < WC1) { src = Wm; dst = Wm_b; }
    else {
        j -= WC1;
        if (j < WC2) { src = Wa; dst = Wa_b; }
        else {
            j -= WC2;
            if (j >= WC3) return;
            src = Wf; dst = Wf_b;
        }
    }
    float4 v = reinterpret_cast<const float4*>(src)[j];
    ushort4 o;
    o.x = f2b(v.x); o.y = f2b(v.y); o.z = f2b(v.z); o.w = f2b(v.w);
    reinterpret_cast<ushort4*>(dst)[j] = o;
}

// ---------------- CSR build ----------------
__global__ void k_count(const int* __restrict__ dst, int* __restrict__ deg) {
    int e = blockIdx.x * blockDim.x + threadIdx.x;
    if (e < EE) atomicAdd(&deg[dst[e]], 1);
}

// multi-block exclusive scan: phase 1 (per-block scan + block sums)
__global__ __launch_bounds__(256) void k_scan1(const int* __restrict__ deg, int* __restrict__ off,
                                               int* __restrict__ bsum) {
    __shared__ int ws[4];
    int tid = threadIdx.x, lane = tid & 63, wv = tid >> 6;
    int i = blockIdx.x * 256 + tid;
    int v = (i < NN) ? deg[i] : 0;
    int x = v;
    #pragma unroll
    for (int o = 1; o < 64; o <<= 1) { int t = __shfl_up(x, o); if (lane >= o) x += t; }
    if (lane == 63) ws[wv] = x;
    __syncthreads();
    int wbase = 0;
    #pragma unroll
    for (int p = 0; p < 3; ++p) if (p < wv) wbase += ws[p];
    if (i < NN) off[i] = wbase + x - v;
    if (tid == 255) bsum[blockIdx.x] = wbase + x;
}

// phase 2: scan the NB block sums (single block), write grand total to off[NN]
__global__ __launch_bounds__(256) void k_scan2(const int* __restrict__ bsum, int* __restrict__ boff,
                                               int* __restrict__ off) {
    __shared__ int ws[4];
    int tid = threadIdx.x, lane = tid & 63, wv = tid >> 6;
    int v = (tid < NB) ? bsum[tid] : 0;
    int x = v;
    #pragma unroll
    for (int o = 1; o < 64; o <<= 1) { int t = __shfl_up(x, o); if (lane >= o) x += t; }
    if (lane == 63) ws[wv] = x;
    __syncthreads();
    int wbase = 0;
    #pragma unroll
    for (int p = 0; p < 3; ++p) if (p < wv) wbase += ws[p];
    if (tid < NB) boff[tid] = wbase + x - v;
    if (tid == 255) off[NN] = wbase + x;
}

// phase 3: add block offsets, init cursor
__global__ __launch_bounds__(256) void k_scan3(const int* __restrict__ boff, int* __restrict__ off,
                                               int* __restrict__ cursor) {
    int i = blockIdx.x * 256 + threadIdx.x;
    if (i < NN) {
        int o = off[i] + boff[blockIdx.x];
        off[i] = o;
        cursor[i] = o;
    }
}

__global__ void k_fill(const int* __restrict__ src, const int* __restrict__ dst,
                       int* __restrict__ cursor, int* __restrict__ csr) {
    int e = blockIdx.x * blockDim.x + threadIdx.x;
    if (e < EE) {
        int d = dst[e];
        int p = atomicAdd(&cursor[d], 1);
        csr[p] = src[e];
    }
}

__global__ void k_goff(const int* __restrict__ batch, int* __restrict__ goff) {
    int i = blockIdx.x * blockDim.x + threadIdx.x;
    if (i >= NN) return;
    int b = batch[i];
    int prev = (i == 0) ? -1 : batch[i - 1];
    for (int g = prev + 1; g <= b; ++g) goff[g] = i;
    if (i == NN - 1) for (int g = b + 1; g <= GG; ++g) goff[g] = NN;
}

// ---------------- MFMA GEMM: Y = leaky(X @ W^T + b) [+ resid] [+ fused gate] ----------------
// MFMA 16x16x32: A row = lane&15, k = kc*32 + (lane>>4)*8 + j; B col = lane&15, same k map.
// D: col = lane&15, row = (lane>>4)*4 + reg (HW-verified).
// GATE: gate[n] = sum_col v[n,col] * wgf[col] + bg0, reduced over the 16-lane lo-group.
template<int KDIM, bool TWO_IN, bool RESID, bool GATE>
__global__ __launch_bounds__(256) void k_mfma(
    const unsigned short* __restrict__ X1b, const unsigned short* __restrict__ X2b,
    const unsigned short* __restrict__ Wb, const float* __restrict__ bias,
    unsigned short* __restrict__ Yb, float* __restrict__ Yf, const float* __restrict__ resid,
    const float* __restrict__ wgf, const float* __restrict__ bgp, float* __restrict__ gate)
{
    const int tid = threadIdx.x;
    const int wv = tid >> 6, lane = tid & 63;
    const int lo = lane & 15, hi = lane >> 4;
    const int n0 = blockIdx.x * 64;
    const int arow = n0 + wv * 16 + lo;
    const bool rvalid = arow < NN;

    f32x4 acc[8];
    #pragma unroll
    for (int t = 0; t < 8; ++t) acc[t] = (f32x4){0.f, 0.f, 0.f, 0.f};

    constexpr int KCH = KDIM / 32;
    #pragma unroll
    for (int kc = 0; kc < KCH; ++kc) {
        const int k = kc * 32 + hi * 8;
        bf16x8 a = (bf16x8)(short)0;
        if (rvalid) {
            if (TWO_IN) {
                const unsigned short* base = (k < 128) ? &X1b[(size_t)arow * 128 + k]
                                                       : &X2b[(size_t)arow * 128 + (k - 128)];
                a = *reinterpret_cast<const bf16x8*>(base);
            } else {
                a = *reinterpret_cast<const bf16x8*>(&X1b[(size_t)arow * KDIM + k]);
            }
        }
        #pragma unroll
        for (int t = 0; t < 8; ++t) {
            const int o = t * 16 + lo;
            bf16x8 b = *reinterpret_cast<const bf16x8*>(&Wb[(size_t)o * KDIM + k]);
            acc[t] = __builtin_amdgcn_mfma_f32_16x16x32_bf16(a, b, acc[t], 0, 0, 0);
        }
    }

    const int orow = n0 + wv * 16 + hi * 4;
    #pragma unroll
    for (int t = 0; t < 8; ++t) {
        const int col = t * 16 + lo;
        const float bc = bias[col];
        #pragma unroll
        for (int r = 0; r < 4; ++r) {
            const int n = orow + r;
            float v = lk(acc[t][r] + bc);
            if (RESID) v += (n < NN) ? resid[(size_t)n * 128 + col] : 0.f;
            acc[t][r] = v;
            if (n < NN) {
                if (RESID) Yf[(size_t)n * 128 + col] = v;
                Yb[(size_t)n * 128 + col] = f2b(v);
            }
        }
    }

    if (GATE) {
        const float bg0 = bgp[0];
        float wgl[8];
        #pragma unroll
        for (int t = 0; t < 8; ++t) wgl[t] = wgf[t * 16 + lo];
        #pragma unroll
        for (int r = 0; r < 4; ++r) {
            float gsum = 0.f;
            #pragma unroll
            for (int t = 0; t < 8; ++t) gsum += acc[t][r] * wgl[t];
            #pragma unroll
            for (int o = 8; o > 0; o >>= 1) gsum += __shfl_xor(gsum, o);
            const int n = orow + r;
            if (lo == 0 && n < NN) gate[n] = gsum + bg0;
        }
    }
}

// ---------------- scatter-max via CSR: one wave per node, 8 edges/iter, bf16 ----------------
__global__ __launch_bounds__(256) void k_aggmax(const unsigned short* __restrict__ yb,
                                                const int* __restrict__ off,
                                                const int* __restrict__ csr,
                                                unsigned short* __restrict__ aggb) {
    int gtid = blockIdx.x * blockDim.x + threadIdx.x;
    int node = gtid >> 6;
    if (node >= NN) return;
    int lane = threadIdx.x & 63;
    int slot = lane >> 4, c8 = (lane & 15) * 8;
    int b = off[node], e = off[node + 1];
    int deg = e - b;
    float m[8];
    #pragma unroll
    for (int j = 0; j < 8; ++j) m[j] = -3.4e38f;
    if (deg > 0) {
        int T = (deg + 7) >> 3;
        for (int it = 0; it < T; ++it) {
            int p0 = b + it * 8 + slot;
            int p1 = p0 + 4;
            int i0 = csr[p0 < e ? p0 : b];
            int i1 = csr[p1 < e ? p1 : b];
            bf16x8 v0 = *reinterpret_cast<const bf16x8*>(&yb[(size_t)i0 * 128 + c8]);
            bf16x8 v1 = *reinterpret_cast<const bf16x8*>(&yb[(size_t)i1 * 128 + c8]);
            #pragma unroll
            for (int j = 0; j < 8; ++j) m[j] = fmaxf(m[j], fmaxf(b2f(v0[j]), b2f(v1[j])));
        }
    }
    #pragma unroll
    for (int j = 0; j < 8; ++j) m[j] = fmaxf(m[j], __shfl_xor(m[j], 16));
    #pragma unroll
    for (int j = 0; j < 8; ++j) m[j] = fmaxf(m[j], __shfl_xor(m[j], 32));
    if (slot == 0) {
        bf16x8 o;
        #pragma unroll
        for (int j = 0; j < 8; ++j) o[j] = (deg > 0) ? (short)f2b(m[j]) : (short)0;
        *reinterpret_cast<bf16x8*>(&aggb[(size_t)node * 128 + c8]) = o;
    }
}

// ---------------- per-graph softmax stats (deterministic) ----------------
__global__ __launch_bounds__(256) void k_gstats(const float* __restrict__ gate, const int* __restrict__ goff,
                                                float* __restrict__ efac, float* __restrict__ invden) {
    __shared__ float red[256];
    int g = blockIdx.x;
    int tid = threadIdx.x;
    int b = goff[g], e = goff[g + 1];
    float m = -3.4e38f;
    for (int i = b + tid; i < e; i += 256) m = fmaxf(m, gate[i]);
    red[tid] = m; __syncthreads();
    for (int o = 128; o > 0; o >>= 1) { if (tid < o) red[tid] = fmaxf(red[tid], red[tid + o]); __syncthreads(); }
    float gm = red[0];
    __syncthreads();
    float s = 0.f;
    for (int i = b + tid; i < e; i += 256) { float ev = __expf(gate[i] - gm); efac[i] = ev; s += ev; }
    red[tid] = s; __syncthreads();
    for (int o = 128; o > 0; o >>= 1) { if (tid < o) red[tid] += red[tid + o]; __syncthreads(); }
    if (tid == 0) { float d = red[0]; if (d == 0.f) d = 1.f; invden[g] = 1.f / d; }
}

// ---------------- xg partial sums (deterministic order), bf16 feat ----------------
__global__ __launch_bounds__(128) void k_xgpart(const float* __restrict__ efac,
                                                const unsigned short* __restrict__ featb,
                                                const int* __restrict__ goff, float* __restrict__ part) {
    int g = blockIdx.x >> 5, p = blockIdx.x & 31;
    int d = threadIdx.x;
    int b = goff[g], e = goff[g + 1];
    int len = e - b;
    int chunk = (len + XP - 1) / XP;
    int s0 = b + p * chunk;
    int s1 = min(e, s0 + chunk);
    float acc = 0.f;
    #pragma unroll 2
    for (int i = s0; i < s1; ++i) acc += efac[i] * b2f(featb[(size_t)i * 128 + d]);
    part[((size_t)g * XP + p) * 128 + d] = acc;
}

// ---------------- global transform ----------------
__global__ __launch_bounds__(128) void k_gtrans(const float* __restrict__ part, const float* __restrict__ invden,
                                                const float* __restrict__ Wt, const float* __restrict__ bt,
                                                float* __restrict__ xglob) {
    __shared__ float cat[256];
    int g = blockIdx.x;
    int o = threadIdx.x;
    float xgv = 0.f;
    #pragma unroll
    for (int p = 0; p < XP; ++p) xgv += part[((size_t)g * XP + p) * 128 + o];
    cat[o] = xgv * invden[g];
    cat[128 + o] = xglob[(size_t)g * 128 + o];
    __syncthreads();
    float accv = bt[o];
    const float4* w4 = reinterpret_cast<const float4*>(&Wt[(size_t)o * 256]);
    #pragma unroll 8
    for (int k4 = 0; k4 < 64; ++k4) {
        float4 wv = w4[k4];
        accv += cat[4 * k4 + 0] * wv.x + cat[4 * k4 + 1] * wv.y + cat[4 * k4 + 2] * wv.z + cat[4 * k4 + 3] * wv.w;
    }
    float outv = lk(accv) + cat[128 + o];
    xglob[(size_t)g * 128 + o] = outv;
}

extern "C" void kernel_launch(void* const* d_in, const int* in_sizes, int n_in,
                              void* d_out, int out_size, void* d_ws, size_t ws_size,
                              hipStream_t stream) {
    const float* x_in  = (const float*)d_in[0];
    const float* xg_in = (const float*)d_in[1];
    const float* Wm = (const float*)d_in[3];
    const float* bm = (const float*)d_in[4];
    const float* Wa = (const float*)d_in[5];
    const float* ba = (const float*)d_in[6];
    const float* Wg = (const float*)d_in[7];
    const float* bg = (const float*)d_in[8];
    const float* Wf = (const float*)d_in[9];
    const float* bf = (const float*)d_in[10];
    const float* Wt = (const float*)d_in[11];
    const float* bt = (const float*)d_in[12];
    const int* eidx  = (const int*)d_in[13];
    const int* batch = (const int*)d_in[14];

    float* xout  = (float*)d_out;                 // [N,128] evolving x (f32 carry)
    float* xglob = xout + (size_t)NN * DD;        // [G,128] evolving x_global

    char* w = (char*)d_ws;
    unsigned short* yb   = (unsigned short*)w; w += (size_t)NN * DD * 2;  // msg / feat bf16
    unsigned short* aggb = (unsigned short*)w; w += (size_t)NN * DD * 2;
    unsigned short* xb   = (unsigned short*)w; w += (size_t)NN * DD * 2;  // bf16 shadow of x
    unsigned short* Wm_b = (unsigned short*)w; w += (size_t)STEPS * DD * DD * 2;
    unsigned short* Wa_b = (unsigned short*)w; w += (size_t)STEPS * DD * 2 * DD * 2;
    unsigned short* Wf_b = (unsigned short*)w; w += (size_t)STEPS * DD * DD * 2;
    float* gate   = (float*)w; w += (size_t)NN * 4;
    float* efac   = (float*)w; w += (size_t)NN * 4;
    float* part   = (float*)w; w += (size_t)GG * XP * DD * 4;
    float* invden = (float*)w; w += (size_t)GG * 4;
    int* deg    = (int*)w; w += (size_t)(NN + 1) * 4;
    int* off    = (int*)w; w += (size_t)(NN + 1) * 4;
    int* cursor = (int*)w; w += (size_t)NN * 4;
    int* csr    = (int*)w; w += (size_t)EE * 4;
    int* goff   = (int*)w; w += (size_t)(GG + 1) * 4;
    int* bsum   = (int*)w; w += (size_t)NB * 4;
    int* boff   = (int*)w; w += (size_t)NB * 4;

    const int* srcI = eidx;
    const int* dstI = eidx + EE;

    hipMemcpyAsync(xout,  x_in,  (size_t)NN * DD * 4, hipMemcpyDeviceToDevice, stream);
    hipMemcpyAsync(xglob, xg_in, (size_t)GG * DD * 4, hipMemcpyDeviceToDevice, stream);

    // one-time conversions
    k_f2b<<<cdiv(NN * DD / 4, 256), 256, 0, stream>>>(x_in, xb, NN * DD / 4);
    k_wcvt<<<cdiv(WC1 + WC2 + WC3, 256), 256, 0, stream>>>(Wm, Wa, Wf, Wm_b, Wa_b, Wf_b);

    // CSR by dst (once per call; reused across steps)
    hipMemsetAsync(deg, 0, (size_t)NN * 4, stream);
    k_count<<<cdiv(EE, 256), 256, 0, stream>>>(dstI, deg);
    k_scan1<<<NB, 256, 0, stream>>>(deg, off, bsum);
    k_scan2<<<1, 256, 0, stream>>>(bsum, boff, off);
    k_scan3<<<NB, 256, 0, stream>>>(boff, off, cursor);
    k_fill<<<cdiv(EE, 256), 256, 0, stream>>>(srcI, dstI, cursor, csr);
    k_goff<<<cdiv(NN, 256), 256, 0, stream>>>(batch, goff);

    const int gemmGrid = cdiv(NN, 64);            // 782
    const int aggGrid  = cdiv(NN * 64, 256);      // 12500

    for (int i = 0; i < STEPS; ++i) {
        const unsigned short* Wmi = Wm_b + (size_t)i * DD * DD;
        const float* bmi = bm + (size_t)i * DD;
        const unsigned short* Wai = Wa_b + (size_t)i * DD * 2 * DD;
        const float* bai = ba + (size_t)i * DD;
        const float* Wgi = Wg + (size_t)i * DD;
        const float* bgi = bg + (size_t)i;
        const unsigned short* Wfi = Wf_b + (size_t)i * DD * DD;
        const float* bfi = bf + (size_t)i * DD;
        const float* Wti = Wt + (size_t)i * DD * 2 * DD;
        const float* bti = bt + (size_t)i * DD;

        // yb = bf16(leaky(x @ Wm^T + bm))
        k_mfma<128, false, false, false><<<gemmGrid, 256, 0, stream>>>(
            xb, nullptr, Wmi, bmi, yb, nullptr, nullptr, nullptr, nullptr, nullptr);
        // aggb[n] = max over in-edges of yb[src] (exact in bf16)
        k_aggmax<<<aggGrid, 256, 0, stream>>>(yb, off, csr, aggb);
        // x = leaky([x, agg] @ Wa^T + ba) + x ; writes f32 xout, bf16 xb, and fused gate
        k_mfma<256, true, true, true><<<gemmGrid, 256, 0, stream>>>(
            xb, aggb, Wai, bai, xb, xout, xout, Wgi, bgi, gate);
        // feat = bf16(leaky(x @ Wf^T + bf))  (reuse yb)
        k_mfma<128, false, false, false><<<gemmGrid, 256, 0, stream>>>(
            xb, nullptr, Wfi, bfi, yb, nullptr, nullptr, nullptr, nullptr, nullptr);
        // per-graph softmax stats
        k_gstats<<<GG, 256, 0, stream>>>(gate, goff, efac, invden);
        // xg partials and global transform
        k_xgpart<<<GG * XP, 128, 0, stream>>>(efac, yb, goff, part);
        k_gtrans<<<GG, 128, 0, stream>>>(part, invden, Wti, bti, xglob);
    }
}

// Round 9
// 603.056 us; speedup vs baseline: 1.2556x; 1.1016x over previous
//
#include <hip/hip_runtime.h>
#include <hip/hip_bf16.h>

#define NN 50000
#define EE 640000
#define DD 128
#define GG 64
#define STEPS 4
#define XP 32
#define NB 196   // cdiv(NN,256) scan blocks

static inline int cdiv(int a, int b) { return (a + b - 1) / b; }

typedef __attribute__((ext_vector_type(8))) short bf16x8;
typedef __attribute__((ext_vector_type(4))) float f32x4;

__device__ __forceinline__ float lk(float z) { return z >= 0.f ? z : 0.01f * z; }
__device__ __forceinline__ float b2f(short b) { return __uint_as_float(((unsigned)(unsigned short)b) << 16); }
__device__ __forceinline__ unsigned short f2b(float f) {
    unsigned u = __float_as_uint(f);
    return (unsigned short)((u + 0x7FFFu + ((u >> 16) & 1u)) >> 16);   // RNE
}

// ---------------- fp32 -> bf16 conversion (vec4) ----------------
__global__ void k_f2b(const float* __restrict__ in, unsigned short* __restrict__ out, int n4) {
    int i = blockIdx.x * blockDim.x + threadIdx.x;
    if (i < n4) {
        float4 v = reinterpret_cast<const float4*>(in)[i];
        ushort4 o;
        o.x = f2b(v.x); o.y = f2b(v.y); o.z = f2b(v.z); o.w = f2b(v.w);
        reinterpret_cast<ushort4*>(out)[i] = o;
    }
}

// fused weight conversion: Wm | Wa | Wf segments (vec4 units)
#define WC1 (STEPS * DD * DD / 4)
#define WC2 (STEPS * DD * 2 * DD / 4)
#define WC3 (STEPS * DD * DD / 4)
__global__ void k_wcvt(const float* __restrict__ Wm, const float* __restrict__ Wa, const float* __restrict__ Wf,
                       unsigned short* __restrict__ Wm_b, unsigned short* __restrict__ Wa_b,
                       unsigned short* __restrict__ Wf_b) {
    int i = blockIdx.x * blockDim.x + threadIdx.x;
    const float* src; unsigned short* dst; int j = i;
    if (j < WC1) { src = Wm; dst = Wm_b; }
    else {
        j -= WC1;
        if (j < WC2) { src = Wa; dst = Wa_b; }
        else {
            j -= WC2;
            if (j >= WC3) return;
            src = Wf; dst = Wf_b;
        }
    }
    float4 v = reinterpret_cast<const float4*>(src)[j];
    ushort4 o;
    o.x = f2b(v.x); o.y = f2b(v.y); o.z = f2b(v.z); o.w = f2b(v.w);
    reinterpret_cast<ushort4*>(dst)[j] = o;
}

// ---------------- CSR build ----------------
__global__ void k_count(const int* __restrict__ dst, int* __restrict__ deg) {
    int e = blockIdx.x * blockDim.x + threadIdx.x;
    if (e < EE) atomicAdd(&deg[dst[e]], 1);
}

// multi-block exclusive scan: phase 1 (per-block scan + block sums)
__global__ __launch_bounds__(256) void k_scan1(const int* __restrict__ deg, int* __restrict__ off,
                                               int* __restrict__ bsum) {
    __shared__ int ws[4];
    int tid = threadIdx.x, lane = tid & 63, wv = tid >> 6;
    int i = blockIdx.x * 256 + tid;
    int v = (i < NN) ? deg[i] : 0;
    int x = v;
    #pragma unroll
    for (int o = 1; o < 64; o <<= 1) { int t = __shfl_up(x, o); if (lane >= o) x += t; }
    if (lane == 63) ws[wv] = x;
    __syncthreads();
    int wbase = 0;
    #pragma unroll
    for (int p = 0; p < 3; ++p) if (p < wv) wbase += ws[p];
    if (i < NN) off[i] = wbase + x - v;
    if (tid == 255) bsum[blockIdx.x] = wbase + x;
}

// phase 2: scan the NB block sums (single block), write grand total to off[NN]
__global__ __launch_bounds__(256) void k_scan2(const int* __restrict__ bsum, int* __restrict__ boff,
                                               int* __restrict__ off) {
    __shared__ int ws[4];
    int tid = threadIdx.x, lane = tid & 63, wv = tid >> 6;
    int v = (tid < NB) ? bsum[tid] : 0;
    int x = v;
    #pragma unroll
    for (int o = 1; o < 64; o <<= 1) { int t = __shfl_up(x, o); if (lane >= o) x += t; }
    if (lane == 63) ws[wv] = x;
    __syncthreads();
    int wbase = 0;
    #pragma unroll
    for (int p = 0; p < 3; ++p) if (p < wv) wbase += ws[p];
    if (tid < NB) boff[tid] = wbase + x - v;
    if (tid == 255) off[NN] = wbase + x;
}

// phase 3: add block offsets, init cursor
__global__ __launch_bounds__(256) void k_scan3(const int* __restrict__ boff, int* __restrict__ off,
                                               int* __restrict__ cursor) {
    int i = blockIdx.x * 256 + threadIdx.x;
    if (i < NN) {
        int o = off[i] + boff[blockIdx.x];
        off[i] = o;
        cursor[i] = o;
    }
}

__global__ void k_fill(const int* __restrict__ src, const int* __restrict__ dst,
                       int* __restrict__ cursor, int* __restrict__ csr) {
    int e = blockIdx.x * blockDim.x + threadIdx.x;
    if (e < EE) {
        int d = dst[e];
        int p = atomicAdd(&cursor[d], 1);
        csr[p] = src[e];
    }
}

__global__ void k_goff(const int* __restrict__ batch, int* __restrict__ goff) {
    int i = blockIdx.x * blockDim.x + threadIdx.x;
    if (i >= NN) return;
    int b = batch[i];
    int prev = (i == 0) ? -1 : batch[i - 1];
    for (int g = prev + 1; g <= b; ++g) goff[g] = i;
    if (i == NN - 1) for (int g = b + 1; g <= GG; ++g) goff[g] = NN;
}

// ---------------- MFMA GEMM: Y = leaky(X @ W^T + b) [+ resid] [+ fused gate] ----------------
// MFMA 16x16x32: A row = lane&15, k = kc*32 + (lane>>4)*8 + j; B col = lane&15, same k map.
// D: col = lane&15, row = (lane>>4)*4 + reg (HW-verified).
// Epilogue: stage leaky(acc+bias) into LDS (col XOR-swizzled by row bit 2 -> 2-way banks),
// then linear coalesced phase: RESID does float4 resid+store+bf16 store+gate per full row
// (32 lanes/row, shfl reduce); non-RESID does 16B bf16x8 stores.
template<int KDIM, bool TWO_IN, bool RESID, bool GATE>
__global__ __launch_bounds__(256) void k_mfma(
    const unsigned short* __restrict__ X1b, const unsigned short* __restrict__ X2b,
    const unsigned short* __restrict__ Wb, const float* __restrict__ bias,
    unsigned short* __restrict__ Yb, float* __restrict__ Yf, const float* __restrict__ resid,
    const float* __restrict__ wgf, const float* __restrict__ bgp, float* __restrict__ gate)
{
    __shared__ float sY[64 * 128];
    const int tid = threadIdx.x;
    const int wv = tid >> 6, lane = tid & 63;
    const int lo = lane & 15, hi = lane >> 4;
    const int n0 = blockIdx.x * 64;
    const int arow = n0 + wv * 16 + lo;
    const bool rvalid = arow < NN;

    f32x4 acc[8];
    #pragma unroll
    for (int t = 0; t < 8; ++t) acc[t] = (f32x4){0.f, 0.f, 0.f, 0.f};

    constexpr int KCH = KDIM / 32;
    #pragma unroll
    for (int kc = 0; kc < KCH; ++kc) {
        const int k = kc * 32 + hi * 8;
        bf16x8 a = (bf16x8)(short)0;
        if (rvalid) {
            if (TWO_IN) {
                const unsigned short* base = (k < 128) ? &X1b[(size_t)arow * 128 + k]
                                                       : &X2b[(size_t)arow * 128 + (k - 128)];
                a = *reinterpret_cast<const bf16x8*>(base);
            } else {
                a = *reinterpret_cast<const bf16x8*>(&X1b[(size_t)arow * KDIM + k]);
            }
        }
        #pragma unroll
        for (int t = 0; t < 8; ++t) {
            const int o = t * 16 + lo;
            bf16x8 b = *reinterpret_cast<const bf16x8*>(&Wb[(size_t)o * KDIM + k]);
            acc[t] = __builtin_amdgcn_mfma_f32_16x16x32_bf16(a, b, acc[t], 0, 0, 0);
        }
    }

    // phase 1: stage leaky(acc + bias) into LDS, col swizzled by row bit 2
    const int lrow = wv * 16 + hi * 4;
    const int swz1 = (hi & 1) << 4;
    #pragma unroll
    for (int t = 0; t < 8; ++t) {
        const int col = (t * 16 + lo) ^ swz1;
        const float bc = bias[t * 16 + lo];
        #pragma unroll
        for (int r = 0; r < 4; ++r)
            sY[(lrow + r) * 128 + col] = lk(acc[t][r] + bc);
    }
    __syncthreads();

    if (RESID) {
        const float bg0 = GATE ? bgp[0] : 0.f;
        #pragma unroll
        for (int it = 0; it < 8; ++it) {
            const int idx = it * 256 + tid;
            const int row = idx >> 5, u4 = (idx & 31) * 4;
            const int n = n0 + row;
            const bool valid = n < NN;
            const int ux = u4 ^ (((row >> 2) & 1) << 4);
            float4 v = *reinterpret_cast<const float4*>(&sY[row * 128 + ux]);
            if (valid) {
                float4 rsd = *reinterpret_cast<const float4*>(&resid[(size_t)n * 128 + u4]);
                v.x += rsd.x; v.y += rsd.y; v.z += rsd.z; v.w += rsd.w;
                *reinterpret_cast<float4*>(&Yf[(size_t)n * 128 + u4]) = v;
                ushort4 ob;
                ob.x = f2b(v.x); ob.y = f2b(v.y); ob.z = f2b(v.z); ob.w = f2b(v.w);
                *reinterpret_cast<ushort4*>(&Yb[(size_t)n * 128 + u4]) = ob;
            }
            if (GATE) {
                float4 wg4 = *reinterpret_cast<const float4*>(&wgf[u4]);
                float gs = valid ? (v.x * wg4.x + v.y * wg4.y + v.z * wg4.z + v.w * wg4.w) : 0.f;
                #pragma unroll
                for (int sh = 16; sh > 0; sh >>= 1) gs += __shfl_xor(gs, sh);
                if ((lane & 31) == 0 && valid) gate[n] = gs + bg0;
            }
        }
    } else {
        #pragma unroll
        for (int it = 0; it < 4; ++it) {
            const int idx = it * 256 + tid;
            const int row = idx >> 4, ub = (idx & 15) * 8;
            const int n = n0 + row;
            if (n < NN) {
                const int ubx = ub ^ (((row >> 2) & 1) << 4);
                bf16x8 ob;
                #pragma unroll
                for (int j = 0; j < 8; ++j) ob[j] = (short)f2b(sY[row * 128 + ubx + j]);
                *reinterpret_cast<bf16x8*>(&Yb[(size_t)n * 128 + ub]) = ob;
            }
        }
    }
}

// ---------------- scatter-max via CSR: one wave per node, 8 edges/iter, bf16 ----------------
__global__ __launch_bounds__(256) void k_aggmax(const unsigned short* __restrict__ yb,
                                                const int* __restrict__ off,
                                                const int* __restrict__ csr,
                                                unsigned short* __restrict__ aggb) {
    int gtid = blockIdx.x * blockDim.x + threadIdx.x;
    int node = gtid >> 6;
    if (node >= NN) return;
    int lane = threadIdx.x & 63;
    int slot = lane >> 4, c8 = (lane & 15) * 8;
    int b = off[node], e = off[node + 1];
    int deg = e - b;
    float m[8];
    #pragma unroll
    for (int j = 0; j < 8; ++j) m[j] = -3.4e38f;
    if (deg > 0) {
        int T = (deg + 7) >> 3;
        for (int it = 0; it < T; ++it) {
            int p0 = b + it * 8 + slot;
            int p1 = p0 + 4;
            int i0 = csr[p0 < e ? p0 : b];
            int i1 = csr[p1 < e ? p1 : b];
            bf16x8 v0 = *reinterpret_cast<const bf16x8*>(&yb[(size_t)i0 * 128 + c8]);
            bf16x8 v1 = *reinterpret_cast<const bf16x8*>(&yb[(size_t)i1 * 128 + c8]);
            #pragma unroll
            for (int j = 0; j < 8; ++j) m[j] = fmaxf(m[j], fmaxf(b2f(v0[j]), b2f(v1[j])));
        }
    }
    #pragma unroll
    for (int j = 0; j < 8; ++j) m[j] = fmaxf(m[j], __shfl_xor(m[j], 16));
    #pragma unroll
    for (int j = 0; j < 8; ++j) m[j] = fmaxf(m[j], __shfl_xor(m[j], 32));
    if (slot == 0) {
        bf16x8 o;
        #pragma unroll
        for (int j = 0; j < 8; ++j) o[j] = (deg > 0) ? (short)f2b(m[j]) : (short)0;
        *reinterpret_cast<bf16x8*>(&aggb[(size_t)node * 128 + c8]) = o;
    }
}

// ---------------- per-graph softmax stats (deterministic) ----------------
__global__ __launch_bounds__(256) void k_gstats(const float* __restrict__ gate, const int* __restrict__ goff,
                                                float* __restrict__ efac, float* __restrict__ invden) {
    __shared__ float red[256];
    int g = blockIdx.x;
    int tid = threadIdx.x;
    int b = goff[g], e = goff[g + 1];
    float m = -3.4e38f;
    for (int i = b + tid; i < e; i += 256) m = fmaxf(m, gate[i]);
    red[tid] = m; __syncthreads();
    for (int o = 128; o > 0; o >>= 1) { if (tid < o) red[tid] = fmaxf(red[tid], red[tid + o]); __syncthreads(); }
    float gm = red[0];
    __syncthreads();
    float s = 0.f;
    for (int i = b + tid; i < e; i += 256) { float ev = __expf(gate[i] - gm); efac[i] = ev; s += ev; }
    red[tid] = s; __syncthreads();
    for (int o = 128; o > 0; o >>= 1) { if (tid < o) red[tid] += red[tid + o]; __syncthreads(); }
    if (tid == 0) { float d = red[0]; if (d == 0.f) d = 1.f; invden[g] = 1.f / d; }
}

// ---------------- xg partial sums (deterministic order), bf16 feat ----------------
__global__ __launch_bounds__(128) void k_xgpart(const float* __restrict__ efac,
                                                const unsigned short* __restrict__ featb,
                                                const int* __restrict__ goff, float* __restrict__ part) {
    int g = blockIdx.x >> 5, p = blockIdx.x & 31;
    int d = threadIdx.x;
    int b = goff[g], e = goff[g + 1];
    int len = e - b;
    int chunk = (len + XP - 1) / XP;
    int s0 = b + p * chunk;
    int s1 = min(e, s0 + chunk);
    float acc = 0.f;
    #pragma unroll 2
    for (int i = s0; i < s1; ++i) acc += efac[i] * b2f(featb[(size_t)i * 128 + d]);
    part[((size_t)g * XP + p) * 128 + d] = acc;
}

// ---------------- global transform ----------------
__global__ __launch_bounds__(128) void k_gtrans(const float* __restrict__ part, const float* __restrict__ invden,
                                                const float* __restrict__ Wt, const float* __restrict__ bt,
                                                float* __restrict__ xglob) {
    __shared__ float cat[256];
    int g = blockIdx.x;
    int o = threadIdx.x;
    float xgv = 0.f;
    #pragma unroll
    for (int p = 0; p < XP; ++p) xgv += part[((size_t)g * XP + p) * 128 + o];
    cat[o] = xgv * invden[g];
    cat[128 + o] = xglob[(size_t)g * 128 + o];
    __syncthreads();
    float accv = bt[o];
    const float4* w4 = reinterpret_cast<const float4*>(&Wt[(size_t)o * 256]);
    #pragma unroll 8
    for (int k4 = 0; k4 < 64; ++k4) {
        float4 wv = w4[k4];
        accv += cat[4 * k4 + 0] * wv.x + cat[4 * k4 + 1] * wv.y + cat[4 * k4 + 2] * wv.z + cat[4 * k4 + 3] * wv.w;
    }
    float outv = lk(accv) + cat[128 + o];
    xglob[(size_t)g * 128 + o] = outv;
}

extern "C" void kernel_launch(void* const* d_in, const int* in_sizes, int n_in,
                              void* d_out, int out_size, void* d_ws, size_t ws_size,
                              hipStream_t stream) {
    const float* x_in  = (const float*)d_in[0];
    const float* xg_in = (const float*)d_in[1];
    const float* Wm = (const float*)d_in[3];
    const float* bm = (const float*)d_in[4];
    const float* Wa = (const float*)d_in[5];
    const float* ba = (const float*)d_in[6];
    const float* Wg = (const float*)d_in[7];
    const float* bg = (const float*)d_in[8];
    const float* Wf = (const float*)d_in[9];
    const float* bf = (const float*)d_in[10];
    const float* Wt = (const float*)d_in[11];
    const float* bt = (const float*)d_in[12];
    const int* eidx  = (const int*)d_in[13];
    const int* batch = (const int*)d_in[14];

    float* xout  = (float*)d_out;                 // [N,128] evolving x (f32 carry)
    float* xglob = xout + (size_t)NN * DD;        // [G,128] evolving x_global

    char* w = (char*)d_ws;
    unsigned short* yb   = (unsigned short*)w; w += (size_t)NN * DD * 2;  // msg / feat bf16
    unsigned short* aggb = (unsigned short*)w; w += (size_t)NN * DD * 2;
    unsigned short* xb   = (unsigned short*)w; w += (size_t)NN * DD * 2;  // bf16 shadow of x
    unsigned short* Wm_b = (unsigned short*)w; w += (size_t)STEPS * DD * DD * 2;
    unsigned short* Wa_b = (unsigned short*)w; w += (size_t)STEPS * DD * 2 * DD * 2;
    unsigned short* Wf_b = (unsigned short*)w; w += (size_t)STEPS * DD * DD * 2;
    float* gate   = (float*)w; w += (size_t)NN * 4;
    float* efac   = (float*)w; w += (size_t)NN * 4;
    float* part   = (float*)w; w += (size_t)GG * XP * DD * 4;
    float* invden = (float*)w; w += (size_t)GG * 4;
    int* deg    = (int*)w; w += (size_t)(NN + 1) * 4;
    int* off    = (int*)w; w += (size_t)(NN + 1) * 4;
    int* cursor = (int*)w; w += (size_t)NN * 4;
    int* csr    = (int*)w; w += (size_t)EE * 4;
    int* goff   = (int*)w; w += (size_t)(GG + 1) * 4;
    int* bsum   = (int*)w; w += (size_t)NB * 4;
    int* boff   = (int*)w; w += (size_t)NB * 4;

    const int* srcI = eidx;
    const int* dstI = eidx + EE;

    hipMemcpyAsync(xout,  x_in,  (size_t)NN * DD * 4, hipMemcpyDeviceToDevice, stream);
    hipMemcpyAsync(xglob, xg_in, (size_t)GG * DD * 4, hipMemcpyDeviceToDevice, stream);

    // one-time conversions
    k_f2b<<<cdiv(NN * DD / 4, 256), 256, 0, stream>>>(x_in, xb, NN * DD / 4);
    k_wcvt<<<cdiv(WC1 + WC2 + WC3, 256), 256, 0, stream>>>(Wm, Wa, Wf, Wm_b, Wa_b, Wf_b);

    // CSR by dst (once per call; reused across steps)
    hipMemsetAsync(deg, 0, (size_t)NN * 4, stream);
    k_count<<<cdiv(EE, 256), 256, 0, stream>>>(dstI, deg);
    k_scan1<<<NB, 256, 0, stream>>>(deg, off, bsum);
    k_scan2<<<1, 256, 0, stream>>>(bsum, boff, off);
    k_scan3<<<NB, 256, 0, stream>>>(boff, off, cursor);
    k_fill<<<cdiv(EE, 256), 256, 0, stream>>>(srcI, dstI, cursor, csr);
    k_goff<<<cdiv(NN, 256), 256, 0, stream>>>(batch, goff);

    const int gemmGrid = cdiv(NN, 64);            // 782
    const int aggGrid  = cdiv(NN * 64, 256);      // 12500

    for (int i = 0; i < STEPS; ++i) {
        const unsigned short* Wmi = Wm_b + (size_t)i * DD * DD;
        const float* bmi = bm + (size_t)i * DD;
        const unsigned short* Wai = Wa_b + (size_t)i * DD * 2 * DD;
        const float* bai = ba + (size_t)i * DD;
        const float* Wgi = Wg + (size_t)i * DD;
        const float* bgi = bg + (size_t)i;
        const unsigned short* Wfi = Wf_b + (size_t)i * DD * DD;
        const float* bfi = bf + (size_t)i * DD;
        const float* Wti = Wt + (size_t)i * DD * 2 * DD;
        const float* bti = bt + (size_t)i * DD;

        // yb = bf16(leaky(x @ Wm^T + bm))
        k_mfma<128, false, false, false><<<gemmGrid, 256, 0, stream>>>(
            xb, nullptr, Wmi, bmi, yb, nullptr, nullptr, nullptr, nullptr, nullptr);
        // aggb[n] = max over in-edges of yb[src] (exact in bf16)
        k_aggmax<<<aggGrid, 256, 0, stream>>>(yb, off, csr, aggb);
        // x = leaky([x, agg] @ Wa^T + ba) + x ; writes f32 xout, bf16 xb, and fused gate
        k_mfma<256, true, true, true><<<gemmGrid, 256, 0, stream>>>(
            xb, aggb, Wai, bai, xb, xout, xout, Wgi, bgi, gate);
        // feat = bf16(leaky(x @ Wf^T + bf))  (reuse yb)
        k_mfma<128, false, false, false><<<gemmGrid, 256, 0, stream>>>(
            xb, nullptr, Wfi, bfi, yb, nullptr, nullptr, nullptr, nullptr, nullptr);
        // per-graph softmax stats
        k_gstats<<<GG, 256, 0, stream>>>(gate, goff, efac, invden);
        // xg partials and global transform
        k_xgpart<<<GG * XP, 128, 0, stream>>>(efac, yb, goff, part);
        k_gtrans<<<GG, 128, 0, stream>>>(part, invden, Wti, bti, xglob);
    }
}

// Round 10
// 569.333 us; speedup vs baseline: 1.3300x; 1.0592x over previous
//
#include <hip/hip_runtime.h>
#include <hip/hip_bf16.h>

#define NN 50000
#define EE 640000
#define DD 128
#define GG 64
#define STEPS 4
#define XP 32
#define NB 196   // cdiv(NN,256) scan blocks

static inline int cdiv(int a, int b) { return (a + b - 1) / b; }

typedef __attribute__((ext_vector_type(8))) short bf16x8;
typedef __attribute__((ext_vector_type(4))) float f32x4;

__device__ __forceinline__ float lk(float z) { return z >= 0.f ? z : 0.01f * z; }
__device__ __forceinline__ float b2f(short b) { return __uint_as_float(((unsigned)(unsigned short)b) << 16); }
__device__ __forceinline__ unsigned short f2b(float f) {
    unsigned u = __float_as_uint(f);
    return (unsigned short)((u + 0x7FFFu + ((u >> 16) & 1u)) >> 16);   // RNE
}

// ---------------- fp32 -> bf16 conversion (vec4) ----------------
__global__ void k_f2b(const float* __restrict__ in, unsigned short* __restrict__ out, int n4) {
    int i = blockIdx.x * blockDim.x + threadIdx.x;
    if (i < n4) {
        float4 v = reinterpret_cast<const float4*>(in)[i];
        ushort4 o;
        o.x = f2b(v.x); o.y = f2b(v.y); o.z = f2b(v.z); o.w = f2b(v.w);
        reinterpret_cast<ushort4*>(out)[i] = o;
    }
}

// fused weight conversion: Wm | Wa | Wf segments (vec4 units)
#define WC1 (STEPS * DD * DD / 4)
#define WC2 (STEPS * DD * 2 * DD / 4)
#define WC3 (STEPS * DD * DD / 4)
__global__ void k_wcvt(const float* __restrict__ Wm, const float* __restrict__ Wa, const float* __restrict__ Wf,
                       unsigned short* __restrict__ Wm_b, unsigned short* __restrict__ Wa_b,
                       unsigned short* __restrict__ Wf_b) {
    int i = blockIdx.x * blockDim.x + threadIdx.x;
    const float* src; unsigned short* dst; int j = i;
    if (j < WC1) { src = Wm; dst = Wm_b; }
    else {
        j -= WC1;
        if (j < WC2) { src = Wa; dst = Wa_b; }
        else {
            j -= WC2;
            if (j >= WC3) return;
            src = Wf; dst = Wf_b;
        }
    }
    float4 v = reinterpret_cast<const float4*>(src)[j];
    ushort4 o;
    o.x = f2b(v.x); o.y = f2b(v.y); o.z = f2b(v.z); o.w = f2b(v.w);
    reinterpret_cast<ushort4*>(dst)[j] = o;
}

// ---------------- CSR build ----------------
__global__ void k_count(const int* __restrict__ dst, int* __restrict__ deg) {
    int e = blockIdx.x * blockDim.x + threadIdx.x;
    if (e < EE) atomicAdd(&deg[dst[e]], 1);
}

__global__ __launch_bounds__(256) void k_scan1(const int* __restrict__ deg, int* __restrict__ off,
                                               int* __restrict__ bsum) {
    __shared__ int ws[4];
    int tid = threadIdx.x, lane = tid & 63, wv = tid >> 6;
    int i = blockIdx.x * 256 + tid;
    int v = (i < NN) ? deg[i] : 0;
    int x = v;
    #pragma unroll
    for (int o = 1; o < 64; o <<= 1) { int t = __shfl_up(x, o); if (lane >= o) x += t; }
    if (lane == 63) ws[wv] = x;
    __syncthreads();
    int wbase = 0;
    #pragma unroll
    for (int p = 0; p < 3; ++p) if (p < wv) wbase += ws[p];
    if (i < NN) off[i] = wbase + x - v;
    if (tid == 255) bsum[blockIdx.x] = wbase + x;
}

__global__ __launch_bounds__(256) void k_scan2(const int* __restrict__ bsum, int* __restrict__ boff,
                                               int* __restrict__ off) {
    __shared__ int ws[4];
    int tid = threadIdx.x, lane = tid & 63, wv = tid >> 6;
    int v = (tid < NB) ? bsum[tid] : 0;
    int x = v;
    #pragma unroll
    for (int o = 1; o < 64; o <<= 1) { int t = __shfl_up(x, o); if (lane >= o) x += t; }
    if (lane == 63) ws[wv] = x;
    __syncthreads();
    int wbase = 0;
    #pragma unroll
    for (int p = 0; p < 3; ++p) if (p < wv) wbase += ws[p];
    if (tid < NB) boff[tid] = wbase + x - v;
    if (tid == 255) off[NN] = wbase + x;
}

__global__ __launch_bounds__(256) void k_scan3(const int* __restrict__ boff, int* __restrict__ off,
                                               int* __restrict__ cursor) {
    int i = blockIdx.x * 256 + threadIdx.x;
    if (i < NN) {
        int o = off[i] + boff[blockIdx.x];
        off[i] = o;
        cursor[i] = o;
    }
}

__global__ void k_fill(const int* __restrict__ src, const int* __restrict__ dst,
                       int* __restrict__ cursor, int* __restrict__ csr) {
    int e = blockIdx.x * blockDim.x + threadIdx.x;
    if (e < EE) {
        int d = dst[e];
        int p = atomicAdd(&cursor[d], 1);
        csr[p] = src[e];
    }
}

__global__ void k_goff(const int* __restrict__ batch, int* __restrict__ goff) {
    int i = blockIdx.x * blockDim.x + threadIdx.x;
    if (i >= NN) return;
    int b = batch[i];
    int prev = (i == 0) ? -1 : batch[i - 1];
    for (int g = prev + 1; g <= b; ++g) goff[g] = i;
    if (i == NN - 1) for (int g = b + 1; g <= GG; ++g) goff[g] = NN;
}

// ---------------- MFMA GEMM, 32-row tiles, col-split waves ----------------
// Block: 256 thr = 4 waves; tile 32 rows x 128 cols. Wave w: rows (w>>1)*16+[0,16),
// cols (w&1)*64+[0,64) = 4 MFMA tiles (8 with OUT2, sharing the A-frag).
// MFMA 16x16x32: A row = lane&15, k = kc*32+(lane>>4)*8+j; B col = lane&15; D col=lane&15,
// row=(lane>>4)*4+reg. Epilogue: LDS-stage (XOR bank swizzle), then linear coalesced I/O.
// OUT2: second weight/bias -> Yb2 (fused feat_i + msg_{i+1}).
template<int KDIM, bool TWO_IN, bool RESID, bool GATE, bool OUT2>
__global__ __launch_bounds__(256) void k_mfma(
    const unsigned short* __restrict__ X1b, const unsigned short* __restrict__ X2b,
    const unsigned short* __restrict__ W1, const float* __restrict__ b1,
    const unsigned short* __restrict__ W2, const float* __restrict__ b2,
    unsigned short* __restrict__ Yb1, unsigned short* __restrict__ Yb2,
    float* __restrict__ Yf, const float* __restrict__ resid,
    const float* __restrict__ wgf, const float* __restrict__ bgp, float* __restrict__ gate)
{
    __shared__ float sY[32 * 128];
    const int tid = threadIdx.x;
    const int wv = tid >> 6, lane = tid & 63;
    const int lo = lane & 15, hi = lane >> 4;
    const int rw = wv >> 1, cw = wv & 1;
    const int n0 = blockIdx.x * 32;
    const int arow = n0 + rw * 16 + lo;
    const bool rvalid = arow < NN;

    f32x4 acc1[4], acc2[4];
    #pragma unroll
    for (int t = 0; t < 4; ++t) { acc1[t] = (f32x4){0.f,0.f,0.f,0.f}; acc2[t] = (f32x4){0.f,0.f,0.f,0.f}; }

    constexpr int KCH = KDIM / 32;
    #pragma unroll
    for (int kc = 0; kc < KCH; ++kc) {
        const int k = kc * 32 + hi * 8;
        bf16x8 a = (bf16x8)(short)0;
        if (rvalid) {
            if (TWO_IN) {
                const unsigned short* base = (k < 128) ? &X1b[(size_t)arow * 128 + k]
                                                       : &X2b[(size_t)arow * 128 + (k - 128)];
                a = *reinterpret_cast<const bf16x8*>(base);
            } else {
                a = *reinterpret_cast<const bf16x8*>(&X1b[(size_t)arow * KDIM + k]);
            }
        }
        #pragma unroll
        for (int t = 0; t < 4; ++t) {
            const int o = cw * 64 + t * 16 + lo;
            bf16x8 bv = *reinterpret_cast<const bf16x8*>(&W1[(size_t)o * KDIM + k]);
            acc1[t] = __builtin_amdgcn_mfma_f32_16x16x32_bf16(a, bv, acc1[t], 0, 0, 0);
            if (OUT2) {
                bf16x8 bv2 = *reinterpret_cast<const bf16x8*>(&W2[(size_t)o * KDIM + k]);
                acc2[t] = __builtin_amdgcn_mfma_f32_16x16x32_bf16(a, bv2, acc2[t], 0, 0, 0);
            }
        }
    }

    // stage output 1: leaky(acc1 + b1), col swizzled by row bit 2 (hi&1)
    const int lrow = rw * 16 + hi * 4;
    const int swz = (hi & 1) << 4;
    #pragma unroll
    for (int t = 0; t < 4; ++t) {
        const int oc = cw * 64 + t * 16 + lo;
        const int col = oc ^ swz;
        const float bc = b1[oc];
        #pragma unroll
        for (int r = 0; r < 4; ++r)
            sY[(lrow + r) * 128 + col] = lk(acc1[t][r] + bc);
    }
    __syncthreads();

    if (RESID) {
        const float bg0 = GATE ? bgp[0] : 0.f;
        #pragma unroll
        for (int it = 0; it < 4; ++it) {
            const int idx = it * 256 + tid;
            const int row = idx >> 5, u4 = (idx & 31) * 4;
            const int n = n0 + row;
            const bool valid = n < NN;
            const int ux = u4 ^ (((row >> 2) & 1) << 4);
            float4 v = *reinterpret_cast<const float4*>(&sY[row * 128 + ux]);
            if (valid) {
                float4 rsd = *reinterpret_cast<const float4*>(&resid[(size_t)n * 128 + u4]);
                v.x += rsd.x; v.y += rsd.y; v.z += rsd.z; v.w += rsd.w;
                *reinterpret_cast<float4*>(&Yf[(size_t)n * 128 + u4]) = v;
                ushort4 ob;
                ob.x = f2b(v.x); ob.y = f2b(v.y); ob.z = f2b(v.z); ob.w = f2b(v.w);
                *reinterpret_cast<ushort4*>(&Yb1[(size_t)n * 128 + u4]) = ob;
            }
            if (GATE) {
                float4 wg4 = *reinterpret_cast<const float4*>(&wgf[u4]);
                float gs = valid ? (v.x * wg4.x + v.y * wg4.y + v.z * wg4.z + v.w * wg4.w) : 0.f;
                #pragma unroll
                for (int sh = 16; sh > 0; sh >>= 1) gs += __shfl_xor(gs, sh);
                if ((lane & 31) == 0 && valid) gate[n] = gs + bg0;
            }
        }
    } else {
        #pragma unroll
        for (int it = 0; it < 2; ++it) {
            const int idx = it * 256 + tid;
            const int row = idx >> 4, ub = (idx & 15) * 8;
            const int n = n0 + row;
            if (n < NN) {
                const int ubx = ub ^ (((row >> 2) & 1) << 4);
                bf16x8 ob;
                #pragma unroll
                for (int j = 0; j < 8; ++j) ob[j] = (short)f2b(sY[row * 128 + ubx + j]);
                *reinterpret_cast<bf16x8*>(&Yb1[(size_t)n * 128 + ub]) = ob;
            }
        }
    }

    if (OUT2) {
        __syncthreads();   // all reads of sY done before restaging
        #pragma unroll
        for (int t = 0; t < 4; ++t) {
            const int oc = cw * 64 + t * 16 + lo;
            const int col = oc ^ swz;
            const float bc = b2[oc];
            #pragma unroll
            for (int r = 0; r < 4; ++r)
                sY[(lrow + r) * 128 + col] = lk(acc2[t][r] + bc);
        }
        __syncthreads();
        #pragma unroll
        for (int it = 0; it < 2; ++it) {
            const int idx = it * 256 + tid;
            const int row = idx >> 4, ub = (idx & 15) * 8;
            const int n = n0 + row;
            if (n < NN) {
                const int ubx = ub ^ (((row >> 2) & 1) << 4);
                bf16x8 ob;
                #pragma unroll
                for (int j = 0; j < 8; ++j) ob[j] = (short)f2b(sY[row * 128 + ubx + j]);
                *reinterpret_cast<bf16x8*>(&Yb2[(size_t)n * 128 + ub]) = ob;
            }
        }
    }
}

// ---------------- scatter-max via CSR: one wave per node, 8 edges/iter, bf16 ----------------
__global__ __launch_bounds__(256) void k_aggmax(const unsigned short* __restrict__ yb,
                                                const int* __restrict__ off,
                                                const int* __restrict__ csr,
                                                unsigned short* __restrict__ aggb) {
    int gtid = blockIdx.x * blockDim.x + threadIdx.x;
    int node = gtid >> 6;
    if (node >= NN) return;
    int lane = threadIdx.x & 63;
    int slot = lane >> 4, c8 = (lane & 15) * 8;
    int b = off[node], e = off[node + 1];
    int deg = e - b;
    float m[8];
    #pragma unroll
    for (int j = 0; j < 8; ++j) m[j] = -3.4e38f;
    if (deg > 0) {
        int T = (deg + 7) >> 3;
        for (int it = 0; it < T; ++it) {
            int p0 = b + it * 8 + slot;
            int p1 = p0 + 4;
            int i0 = csr[p0 < e ? p0 : b];
            int i1 = csr[p1 < e ? p1 : b];
            bf16x8 v0 = *reinterpret_cast<const bf16x8*>(&yb[(size_t)i0 * 128 + c8]);
            bf16x8 v1 = *reinterpret_cast<const bf16x8*>(&yb[(size_t)i1 * 128 + c8]);
            #pragma unroll
            for (int j = 0; j < 8; ++j) m[j] = fmaxf(m[j], fmaxf(b2f(v0[j]), b2f(v1[j])));
        }
    }
    #pragma unroll
    for (int j = 0; j < 8; ++j) m[j] = fmaxf(m[j], __shfl_xor(m[j], 16));
    #pragma unroll
    for (int j = 0; j < 8; ++j) m[j] = fmaxf(m[j], __shfl_xor(m[j], 32));
    if (slot == 0) {
        bf16x8 o;
        #pragma unroll
        for (int j = 0; j < 8; ++j) o[j] = (deg > 0) ? (short)f2b(m[j]) : (short)0;
        *reinterpret_cast<bf16x8*>(&aggb[(size_t)node * 128 + c8]) = o;
    }
}

// ---------------- per-graph softmax stats (deterministic) ----------------
__global__ __launch_bounds__(256) void k_gstats(const float* __restrict__ gate, const int* __restrict__ goff,
                                                float* __restrict__ efac, float* __restrict__ invden) {
    __shared__ float red[256];
    int g = blockIdx.x;
    int tid = threadIdx.x;
    int b = goff[g], e = goff[g + 1];
    float m = -3.4e38f;
    for (int i = b + tid; i < e; i += 256) m = fmaxf(m, gate[i]);
    red[tid] = m; __syncthreads();
    for (int o = 128; o > 0; o >>= 1) { if (tid < o) red[tid] = fmaxf(red[tid], red[tid + o]); __syncthreads(); }
    float gm = red[0];
    __syncthreads();
    float s = 0.f;
    for (int i = b + tid; i < e; i += 256) { float ev = __expf(gate[i] - gm); efac[i] = ev; s += ev; }
    red[tid] = s; __syncthreads();
    for (int o = 128; o > 0; o >>= 1) { if (tid < o) red[tid] += red[tid + o]; __syncthreads(); }
    if (tid == 0) { float d = red[0]; if (d == 0.f) d = 1.f; invden[g] = 1.f / d; }
}

// ---------------- xg partial sums (deterministic order), bf16 feat ----------------
__global__ __launch_bounds__(128) void k_xgpart(const float* __restrict__ efac,
                                                const unsigned short* __restrict__ featb,
                                                const int* __restrict__ goff, float* __restrict__ part) {
    int g = blockIdx.x >> 5, p = blockIdx.x & 31;
    int d = threadIdx.x;
    int b = goff[g], e = goff[g + 1];
    int len = e - b;
    int chunk = (len + XP - 1) / XP;
    int s0 = b + p * chunk;
    int s1 = min(e, s0 + chunk);
    float acc = 0.f;
    #pragma unroll 2
    for (int i = s0; i < s1; ++i) acc += efac[i] * b2f(featb[(size_t)i * 128 + d]);
    part[((size_t)g * XP + p) * 128 + d] = acc;
}

// ---------------- global transform ----------------
__global__ __launch_bounds__(128) void k_gtrans(const float* __restrict__ part, const float* __restrict__ invden,
                                                const float* __restrict__ Wt, const float* __restrict__ bt,
                                                float* __restrict__ xglob) {
    __shared__ float cat[256];
    int g = blockIdx.x;
    int o = threadIdx.x;
    float xgv = 0.f;
    #pragma unroll
    for (int p = 0; p < XP; ++p) xgv += part[((size_t)g * XP + p) * 128 + o];
    cat[o] = xgv * invden[g];
    cat[128 + o] = xglob[(size_t)g * 128 + o];
    __syncthreads();
    float accv = bt[o];
    const float4* w4 = reinterpret_cast<const float4*>(&Wt[(size_t)o * 256]);
    #pragma unroll 8
    for (int k4 = 0; k4 < 64; ++k4) {
        float4 wv = w4[k4];
        accv += cat[4 * k4 + 0] * wv.x + cat[4 * k4 + 1] * wv.y + cat[4 * k4 + 2] * wv.z + cat[4 * k4 + 3] * wv.w;
    }
    float outv = lk(accv) + cat[128 + o];
    xglob[(size_t)g * 128 + o] = outv;
}

extern "C" void kernel_launch(void* const* d_in, const int* in_sizes, int n_in,
                              void* d_out, int out_size, void* d_ws, size_t ws_size,
                              hipStream_t stream) {
    const float* x_in  = (const float*)d_in[0];
    const float* xg_in = (const float*)d_in[1];
    const float* Wm = (const float*)d_in[3];
    const float* bm = (const float*)d_in[4];
    const float* Wa = (const float*)d_in[5];
    const float* ba = (const float*)d_in[6];
    const float* Wg = (const float*)d_in[7];
    const float* bg = (const float*)d_in[8];
    const float* Wf = (const float*)d_in[9];
    const float* bf = (const float*)d_in[10];
    const float* Wt = (const float*)d_in[11];
    const float* bt = (const float*)d_in[12];
    const int* eidx  = (const int*)d_in[13];
    const int* batch = (const int*)d_in[14];

    float* xout  = (float*)d_out;                 // [N,128] evolving x (f32 carry)
    float* xglob = xout + (size_t)NN * DD;        // [G,128] evolving x_global

    char* w = (char*)d_ws;
    unsigned short* yb    = (unsigned short*)w; w += (size_t)NN * DD * 2;  // msg bf16
    unsigned short* featb = (unsigned short*)w; w += (size_t)NN * DD * 2;  // feat bf16
    unsigned short* aggb  = (unsigned short*)w; w += (size_t)NN * DD * 2;
    unsigned short* xb    = (unsigned short*)w; w += (size_t)NN * DD * 2;  // bf16 shadow of x
    unsigned short* Wm_b  = (unsigned short*)w; w += (size_t)STEPS * DD * DD * 2;
    unsigned short* Wa_b  = (unsigned short*)w; w += (size_t)STEPS * DD * 2 * DD * 2;
    unsigned short* Wf_b  = (unsigned short*)w; w += (size_t)STEPS * DD * DD * 2;
    float* gate   = (float*)w; w += (size_t)NN * 4;
    float* efac   = (float*)w; w += (size_t)NN * 4;
    float* part   = (float*)w; w += (size_t)GG * XP * DD * 4;
    float* invden = (float*)w; w += (size_t)GG * 4;
    int* deg    = (int*)w; w += (size_t)(NN + 1) * 4;
    int* off    = (int*)w; w += (size_t)(NN + 1) * 4;
    int* cursor = (int*)w; w += (size_t)NN * 4;
    int* csr    = (int*)w; w += (size_t)EE * 4;
    int* goff   = (int*)w; w += (size_t)(GG + 1) * 4;
    int* bsum   = (int*)w; w += (size_t)NB * 4;
    int* boff   = (int*)w; w += (size_t)NB * 4;

    const int* srcI = eidx;
    const int* dstI = eidx + EE;

    hipMemcpyAsync(xout,  x_in,  (size_t)NN * DD * 4, hipMemcpyDeviceToDevice, stream);
    hipMemcpyAsync(xglob, xg_in, (size_t)GG * DD * 4, hipMemcpyDeviceToDevice, stream);

    // one-time conversions
    k_f2b<<<cdiv(NN * DD / 4, 256), 256, 0, stream>>>(x_in, xb, NN * DD / 4);
    k_wcvt<<<cdiv(WC1 + WC2 + WC3, 256), 256, 0, stream>>>(Wm, Wa, Wf, Wm_b, Wa_b, Wf_b);

    // CSR by dst (once per call; reused across steps)
    hipMemsetAsync(deg, 0, (size_t)NN * 4, stream);
    k_count<<<cdiv(EE, 256), 256, 0, stream>>>(dstI, deg);
    k_scan1<<<NB, 256, 0, stream>>>(deg, off, bsum);
    k_scan2<<<1, 256, 0, stream>>>(bsum, boff, off);
    k_scan3<<<NB, 256, 0, stream>>>(boff, off, cursor);
    k_fill<<<cdiv(EE, 256), 256, 0, stream>>>(srcI, dstI, cursor, csr);
    k_goff<<<cdiv(NN, 256), 256, 0, stream>>>(batch, goff);

    const int gemmGrid = cdiv(NN, 32);            // 1563
    const int aggGrid  = cdiv(NN * 64, 256);      // 12500

    // msg_0 = bf16(leaky(x @ Wm[0]^T + bm[0]))
    k_mfma<128, false, false, false, false><<<gemmGrid, 256, 0, stream>>>(
        xb, nullptr, Wm_b, bm, nullptr, nullptr, yb, nullptr, nullptr, nullptr, nullptr, nullptr, nullptr);

    for (int i = 0; i < STEPS; ++i) {
        const float* bai = ba + (size_t)i * DD;
        const unsigned short* Wai = Wa_b + (size_t)i * DD * 2 * DD;
        const float* Wgi = Wg + (size_t)i * DD;
        const float* bgi = bg + (size_t)i;
        const unsigned short* Wfi = Wf_b + (size_t)i * DD * DD;
        const float* bfi = bf + (size_t)i * DD;
        const float* Wti = Wt + (size_t)i * DD * 2 * DD;
        const float* bti = bt + (size_t)i * DD;

        // aggb[n] = max over in-edges of yb[src] (exact in bf16)
        k_aggmax<<<aggGrid, 256, 0, stream>>>(yb, off, csr, aggb);
        // x = leaky([x, agg] @ Wa^T + ba) + x ; writes f32 xout, bf16 xb, fused gate
        k_mfma<256, true, true, true, false><<<gemmGrid, 256, 0, stream>>>(
            xb, aggb, Wai, bai, nullptr, nullptr, xb, nullptr, xout, xout, Wgi, bgi, gate);
        if (i < STEPS - 1) {
            // fused: feat_i -> featb, msg_{i+1} -> yb (both read x_{i+1})
            const unsigned short* Wmn = Wm_b + (size_t)(i + 1) * DD * DD;
            const float* bmn = bm + (size_t)(i + 1) * DD;
            k_mfma<128, false, false, false, true><<<gemmGrid, 256, 0, stream>>>(
                xb, nullptr, Wfi, bfi, Wmn, bmn, featb, yb, nullptr, nullptr, nullptr, nullptr, nullptr);
        } else {
            k_mfma<128, false, false, false, false><<<gemmGrid, 256, 0, stream>>>(
                xb, nullptr, Wfi, bfi, nullptr, nullptr, featb, nullptr, nullptr, nullptr, nullptr, nullptr, nullptr);
        }
        // per-graph softmax stats
        k_gstats<<<GG, 256, 0, stream>>>(gate, goff, efac, invden);
        // xg partials and global transform
        k_xgpart<<<GG * XP, 128, 0, stream>>>(efac, featb, goff, part);
        k_gtrans<<<GG, 128, 0, stream>>>(part, invden, Wti, bti, xglob);
    }
}

// Round 11
// 556.201 us; speedup vs baseline: 1.3614x; 1.0236x over previous
//
#include <hip/hip_runtime.h>
#include <hip/hip_bf16.h>

#define NN 50000
#define EE 640000
#define DD 128
#define GG 64
#define STEPS 4
#define XP 32
#define NB 196   // cdiv(NN,256) scan blocks

static inline int cdiv(int a, int b) { return (a + b - 1) / b; }

typedef __attribute__((ext_vector_type(8))) short bf16x8;
typedef __attribute__((ext_vector_type(4))) float f32x4;

__device__ __forceinline__ float lk(float z) { return z >= 0.f ? z : 0.01f * z; }
__device__ __forceinline__ float b2f(short b) { return __uint_as_float(((unsigned)(unsigned short)b) << 16); }
__device__ __forceinline__ unsigned short f2b(float f) {
    unsigned u = __float_as_uint(f);
    return (unsigned short)((u + 0x7FFFu + ((u >> 16) & 1u)) >> 16);   // RNE
}

// ---------------- fp32 -> bf16 conversion (vec4) ----------------
__global__ void k_f2b(const float* __restrict__ in, unsigned short* __restrict__ out, int n4) {
    int i = blockIdx.x * blockDim.x + threadIdx.x;
    if (i < n4) {
        float4 v = reinterpret_cast<const float4*>(in)[i];
        ushort4 o;
        o.x = f2b(v.x); o.y = f2b(v.y); o.z = f2b(v.z); o.w = f2b(v.w);
        reinterpret_cast<ushort4*>(out)[i] = o;
    }
}

// fused weight conversion: Wm | Wa | Wf segments (vec4 units)
#define WC1 (STEPS * DD * DD / 4)
#define WC2 (STEPS * DD * 2 * DD / 4)
#define WC3 (STEPS * DD * DD / 4)
__global__ void k_wcvt(const float* __restrict__ Wm, const float* __restrict__ Wa, const float* __restrict__ Wf,
                       unsigned short* __restrict__ Wm_b, unsigned short* __restrict__ Wa_b,
                       unsigned short* __restrict__ Wf_b) {
    int i = blockIdx.x * blockDim.x + threadIdx.x;
    const float* src; unsigned short* dst; int j = i;
    if (j < WC1) { src = Wm; dst = Wm_b; }
    else {
        j -= WC1;
        if (j < WC2) { src = Wa; dst = Wa_b; }
        else {
            j -= WC2;
            if (j >= WC3) return;
            src = Wf; dst = Wf_b;
        }
    }
    float4 v = reinterpret_cast<const float4*>(src)[j];
    ushort4 o;
    o.x = f2b(v.x); o.y = f2b(v.y); o.z = f2b(v.z); o.w = f2b(v.w);
    reinterpret_cast<ushort4*>(dst)[j] = o;
}

// ---------------- CSR build ----------------
__global__ void k_count(const int* __restrict__ dst, int* __restrict__ deg) {
    int e = blockIdx.x * blockDim.x + threadIdx.x;
    if (e < EE) atomicAdd(&deg[dst[e]], 1);
}

__global__ __launch_bounds__(256) void k_scan1(const int* __restrict__ deg, int* __restrict__ off,
                                               int* __restrict__ bsum) {
    __shared__ int ws[4];
    int tid = threadIdx.x, lane = tid & 63, wv = tid >> 6;
    int i = blockIdx.x * 256 + tid;
    int v = (i < NN) ? deg[i] : 0;
    int x = v;
    #pragma unroll
    for (int o = 1; o < 64; o <<= 1) { int t = __shfl_up(x, o); if (lane >= o) x += t; }
    if (lane == 63) ws[wv] = x;
    __syncthreads();
    int wbase = 0;
    #pragma unroll
    for (int p = 0; p < 3; ++p) if (p < wv) wbase += ws[p];
    if (i < NN) off[i] = wbase + x - v;
    if (tid == 255) bsum[blockIdx.x] = wbase + x;
}

__global__ __launch_bounds__(256) void k_scan2(const int* __restrict__ bsum, int* __restrict__ boff,
                                               int* __restrict__ off) {
    __shared__ int ws[4];
    int tid = threadIdx.x, lane = tid & 63, wv = tid >> 6;
    int v = (tid < NB) ? bsum[tid] : 0;
    int x = v;
    #pragma unroll
    for (int o = 1; o < 64; o <<= 1) { int t = __shfl_up(x, o); if (lane >= o) x += t; }
    if (lane == 63) ws[wv] = x;
    __syncthreads();
    int wbase = 0;
    #pragma unroll
    for (int p = 0; p < 3; ++p) if (p < wv) wbase += ws[p];
    if (tid < NB) boff[tid] = wbase + x - v;
    if (tid == 255) off[NN] = wbase + x;
}

__global__ __launch_bounds__(256) void k_scan3(const int* __restrict__ boff, int* __restrict__ off,
                                               int* __restrict__ cursor) {
    int i = blockIdx.x * 256 + threadIdx.x;
    if (i < NN) {
        int o = off[i] + boff[blockIdx.x];
        off[i] = o;
        cursor[i] = o;
    }
}

__global__ void k_fill(const int* __restrict__ src, const int* __restrict__ dst,
                       int* __restrict__ cursor, int* __restrict__ csr) {
    int e = blockIdx.x * blockDim.x + threadIdx.x;
    if (e < EE) {
        int d = dst[e];
        int p = atomicAdd(&cursor[d], 1);
        csr[p] = src[e];
    }
}

__global__ void k_goff(const int* __restrict__ batch, int* __restrict__ goff) {
    int i = blockIdx.x * blockDim.x + threadIdx.x;
    if (i >= NN) return;
    int b = batch[i];
    int prev = (i == 0) ? -1 : batch[i - 1];
    for (int g = prev + 1; g <= b; ++g) goff[g] = i;
    if (i == NN - 1) for (int g = b + 1; g <= GG; ++g) goff[g] = NN;
}

// ---------------- MFMA GEMM, 32-row tiles, col-split waves, A-prefetch ----------------
// Block: 256 thr = 4 waves; tile 32 rows x 128 cols. Wave w: rows (w>>1)*16+[0,16),
// cols (w&1)*64+[0,64) = 4 MFMA tiles (8 with OUT2, sharing the A-frag).
// A chunks are ALL prefetched into registers before the MFMA loop (load ILP: 8 in flight).
// GATE: writes efac[n] = expf(gate[n]) directly (softmax without max-subtraction; |gate|<~20).
template<int KDIM, bool TWO_IN, bool RESID, bool GATE, bool OUT2>
__global__ __launch_bounds__(256) void k_mfma(
    const unsigned short* __restrict__ X1b, const unsigned short* __restrict__ X2b,
    const unsigned short* __restrict__ W1, const float* __restrict__ b1,
    const unsigned short* __restrict__ W2, const float* __restrict__ b2,
    unsigned short* __restrict__ Yb1, unsigned short* __restrict__ Yb2,
    float* __restrict__ Yf, const float* __restrict__ resid,
    const float* __restrict__ wgf, const float* __restrict__ bgp, float* __restrict__ efac)
{
    __shared__ float sY[32 * 128];
    const int tid = threadIdx.x;
    const int wv = tid >> 6, lane = tid & 63;
    const int lo = lane & 15, hi = lane >> 4;
    const int rw = wv >> 1, cw = wv & 1;
    const int n0 = blockIdx.x * 32;
    const int arow = n0 + rw * 16 + lo;
    const bool rvalid = arow < NN;

    constexpr int KCH = KDIM / 32;

    // prefetch ALL A chunks (independent loads in flight)
    bf16x8 a[KCH];
    #pragma unroll
    for (int kc = 0; kc < KCH; ++kc) {
        const int k = kc * 32 + hi * 8;
        if (rvalid) {
            if (TWO_IN) {
                const unsigned short* base = (kc < 4) ? &X1b[(size_t)arow * 128 + k]
                                                      : &X2b[(size_t)arow * 128 + (k - 128)];
                a[kc] = *reinterpret_cast<const bf16x8*>(base);
            } else {
                a[kc] = *reinterpret_cast<const bf16x8*>(&X1b[(size_t)arow * KDIM + k]);
            }
        } else {
            a[kc] = (bf16x8)(short)0;
        }
    }

    f32x4 acc1[4], acc2[4];
    #pragma unroll
    for (int t = 0; t < 4; ++t) { acc1[t] = (f32x4){0.f,0.f,0.f,0.f}; acc2[t] = (f32x4){0.f,0.f,0.f,0.f}; }

    #pragma unroll
    for (int kc = 0; kc < KCH; ++kc) {
        const int k = kc * 32 + hi * 8;
        #pragma unroll
        for (int t = 0; t < 4; ++t) {
            const int o = cw * 64 + t * 16 + lo;
            bf16x8 bv = *reinterpret_cast<const bf16x8*>(&W1[(size_t)o * KDIM + k]);
            acc1[t] = __builtin_amdgcn_mfma_f32_16x16x32_bf16(a[kc], bv, acc1[t], 0, 0, 0);
            if (OUT2) {
                bf16x8 bv2 = *reinterpret_cast<const bf16x8*>(&W2[(size_t)o * KDIM + k]);
                acc2[t] = __builtin_amdgcn_mfma_f32_16x16x32_bf16(a[kc], bv2, acc2[t], 0, 0, 0);
            }
        }
    }

    // stage output 1: leaky(acc1 + b1), col swizzled by row bit 2 (hi&1)
    const int lrow = rw * 16 + hi * 4;
    const int swz = (hi & 1) << 4;
    #pragma unroll
    for (int t = 0; t < 4; ++t) {
        const int oc = cw * 64 + t * 16 + lo;
        const int col = oc ^ swz;
        const float bc = b1[oc];
        #pragma unroll
        for (int r = 0; r < 4; ++r)
            sY[(lrow + r) * 128 + col] = lk(acc1[t][r] + bc);
    }
    __syncthreads();

    if (RESID) {
        const float bg0 = GATE ? bgp[0] : 0.f;
        #pragma unroll
        for (int it = 0; it < 4; ++it) {
            const int idx = it * 256 + tid;
            const int row = idx >> 5, u4 = (idx & 31) * 4;
            const int n = n0 + row;
            const bool valid = n < NN;
            const int ux = u4 ^ (((row >> 2) & 1) << 4);
            float4 v = *reinterpret_cast<const float4*>(&sY[row * 128 + ux]);
            if (valid) {
                float4 rsd = *reinterpret_cast<const float4*>(&resid[(size_t)n * 128 + u4]);
                v.x += rsd.x; v.y += rsd.y; v.z += rsd.z; v.w += rsd.w;
                *reinterpret_cast<float4*>(&Yf[(size_t)n * 128 + u4]) = v;
                ushort4 ob;
                ob.x = f2b(v.x); ob.y = f2b(v.y); ob.z = f2b(v.z); ob.w = f2b(v.w);
                *reinterpret_cast<ushort4*>(&Yb1[(size_t)n * 128 + u4]) = ob;
            }
            if (GATE) {
                float4 wg4 = *reinterpret_cast<const float4*>(&wgf[u4]);
                float gs = valid ? (v.x * wg4.x + v.y * wg4.y + v.z * wg4.z + v.w * wg4.w) : 0.f;
                #pragma unroll
                for (int sh = 16; sh > 0; sh >>= 1) gs += __shfl_xor(gs, sh);
                if ((lane & 31) == 0 && valid) efac[n] = __expf(gs + bg0);
            }
        }
    } else {
        #pragma unroll
        for (int it = 0; it < 2; ++it) {
            const int idx = it * 256 + tid;
            const int row = idx >> 4, ub = (idx & 15) * 8;
            const int n = n0 + row;
            if (n < NN) {
                const int ubx = ub ^ (((row >> 2) & 1) << 4);
                bf16x8 ob;
                #pragma unroll
                for (int j = 0; j < 8; ++j) ob[j] = (short)f2b(sY[row * 128 + ubx + j]);
                *reinterpret_cast<bf16x8*>(&Yb1[(size_t)n * 128 + ub]) = ob;
            }
        }
    }

    if (OUT2) {
        __syncthreads();   // all reads of sY done before restaging
        #pragma unroll
        for (int t = 0; t < 4; ++t) {
            const int oc = cw * 64 + t * 16 + lo;
            const int col = oc ^ swz;
            const float bc = b2[oc];
            #pragma unroll
            for (int r = 0; r < 4; ++r)
                sY[(lrow + r) * 128 + col] = lk(acc2[t][r] + bc);
        }
        __syncthreads();
        #pragma unroll
        for (int it = 0; it < 2; ++it) {
            const int idx = it * 256 + tid;
            const int row = idx >> 4, ub = (idx & 15) * 8;
            const int n = n0 + row;
            if (n < NN) {
                const int ubx = ub ^ (((row >> 2) & 1) << 4);
                bf16x8 ob;
                #pragma unroll
                for (int j = 0; j < 8; ++j) ob[j] = (short)f2b(sY[row * 128 + ubx + j]);
                *reinterpret_cast<bf16x8*>(&Yb2[(size_t)n * 128 + ub]) = ob;
            }
        }
    }
}

// ---------------- scatter-max via CSR: one wave per node, 8 edges/iter, bf16 ----------------
__global__ __launch_bounds__(256) void k_aggmax(const unsigned short* __restrict__ yb,
                                                const int* __restrict__ off,
                                                const int* __restrict__ csr,
                                                unsigned short* __restrict__ aggb) {
    int gtid = blockIdx.x * blockDim.x + threadIdx.x;
    int node = gtid >> 6;
    if (node >= NN) return;
    int lane = threadIdx.x & 63;
    int slot = lane >> 4, c8 = (lane & 15) * 8;
    int b = off[node], e = off[node + 1];
    int deg = e - b;
    float m[8];
    #pragma unroll
    for (int j = 0; j < 8; ++j) m[j] = -3.4e38f;
    if (deg > 0) {
        int T = (deg + 7) >> 3;
        for (int it = 0; it < T; ++it) {
            int p0 = b + it * 8 + slot;
            int p1 = p0 + 4;
            int i0 = csr[p0 < e ? p0 : b];
            int i1 = csr[p1 < e ? p1 : b];
            bf16x8 v0 = *reinterpret_cast<const bf16x8*>(&yb[(size_t)i0 * 128 + c8]);
            bf16x8 v1 = *reinterpret_cast<const bf16x8*>(&yb[(size_t)i1 * 128 + c8]);
            #pragma unroll
            for (int j = 0; j < 8; ++j) m[j] = fmaxf(m[j], fmaxf(b2f(v0[j]), b2f(v1[j])));
        }
    }
    #pragma unroll
    for (int j = 0; j < 8; ++j) m[j] = fmaxf(m[j], __shfl_xor(m[j], 16));
    #pragma unroll
    for (int j = 0; j < 8; ++j) m[j] = fmaxf(m[j], __shfl_xor(m[j], 32));
    if (slot == 0) {
        bf16x8 o;
        #pragma unroll
        for (int j = 0; j < 8; ++j) o[j] = (deg > 0) ? (short)f2b(m[j]) : (short)0;
        *reinterpret_cast<bf16x8*>(&aggb[(size_t)node * 128 + c8]) = o;
    }
}

// ---------------- xg partial sums (+ efac partial sums), deterministic order ----------------
__global__ __launch_bounds__(128) void k_xgpart(const float* __restrict__ efac,
                                                const unsigned short* __restrict__ featb,
                                                const int* __restrict__ goff,
                                                float* __restrict__ part, float* __restrict__ parte) {
    int g = blockIdx.x >> 5, p = blockIdx.x & 31;
    int d = threadIdx.x;
    int b = goff[g], e = goff[g + 1];
    int len = e - b;
    int chunk = (len + XP - 1) / XP;
    int s0 = b + p * chunk;
    int s1 = min(e, s0 + chunk);
    float acc = 0.f, acce = 0.f;
    #pragma unroll 2
    for (int i = s0; i < s1; ++i) {
        float ev = efac[i];
        acce += ev;
        acc += ev * b2f(featb[(size_t)i * 128 + d]);
    }
    part[((size_t)g * XP + p) * 128 + d] = acc;
    if (d == 0) parte[(size_t)g * XP + p] = acce;
}

// ---------------- global transform (combines efac partials -> denom) ----------------
__global__ __launch_bounds__(128) void k_gtrans(const float* __restrict__ part, const float* __restrict__ parte,
                                                const float* __restrict__ Wt, const float* __restrict__ bt,
                                                float* __restrict__ xglob) {
    __shared__ float cat[256];
    int g = blockIdx.x;
    int o = threadIdx.x;
    float xgv = 0.f, se = 0.f;
    #pragma unroll
    for (int p = 0; p < XP; ++p) {
        xgv += part[((size_t)g * XP + p) * 128 + o];
        se  += parte[(size_t)g * XP + p];
    }
    if (se == 0.f) se = 1.f;
    cat[o] = xgv / se;
    cat[128 + o] = xglob[(size_t)g * 128 + o];
    __syncthreads();
    float accv = bt[o];
    const float4* w4 = reinterpret_cast<const float4*>(&Wt[(size_t)o * 256]);
    #pragma unroll 8
    for (int k4 = 0; k4 < 64; ++k4) {
        float4 wv = w4[k4];
        accv += cat[4 * k4 + 0] * wv.x + cat[4 * k4 + 1] * wv.y + cat[4 * k4 + 2] * wv.z + cat[4 * k4 + 3] * wv.w;
    }
    float outv = lk(accv) + cat[128 + o];
    xglob[(size_t)g * 128 + o] = outv;
}

extern "C" void kernel_launch(void* const* d_in, const int* in_sizes, int n_in,
                              void* d_out, int out_size, void* d_ws, size_t ws_size,
                              hipStream_t stream) {
    const float* x_in  = (const float*)d_in[0];
    const float* xg_in = (const float*)d_in[1];
    const float* Wm = (const float*)d_in[3];
    const float* bm = (const float*)d_in[4];
    const float* Wa = (const float*)d_in[5];
    const float* ba = (const float*)d_in[6];
    const float* Wg = (const float*)d_in[7];
    const float* bg = (const float*)d_in[8];
    const float* Wf = (const float*)d_in[9];
    const float* bf = (const float*)d_in[10];
    const float* Wt = (const float*)d_in[11];
    const float* bt = (const float*)d_in[12];
    const int* eidx  = (const int*)d_in[13];
    const int* batch = (const int*)d_in[14];

    float* xout  = (float*)d_out;                 // [N,128] evolving x (f32 carry)
    float* xglob = xout + (size_t)NN * DD;        // [G,128] evolving x_global

    char* w = (char*)d_ws;
    unsigned short* yb    = (unsigned short*)w; w += (size_t)NN * DD * 2;  // msg bf16
    unsigned short* featb = (unsigned short*)w; w += (size_t)NN * DD * 2;  // feat bf16
    unsigned short* aggb  = (unsigned short*)w; w += (size_t)NN * DD * 2;
    unsigned short* xb    = (unsigned short*)w; w += (size_t)NN * DD * 2;  // bf16 shadow of x
    unsigned short* Wm_b  = (unsigned short*)w; w += (size_t)STEPS * DD * DD * 2;
    unsigned short* Wa_b  = (unsigned short*)w; w += (size_t)STEPS * DD * 2 * DD * 2;
    unsigned short* Wf_b  = (unsigned short*)w; w += (size_t)STEPS * DD * DD * 2;
    float* efac   = (float*)w; w += (size_t)NN * 4;
    float* part   = (float*)w; w += (size_t)GG * XP * DD * 4;
    float* parte  = (float*)w; w += (size_t)GG * XP * 4;
    int* deg    = (int*)w; w += (size_t)(NN + 1) * 4;
    int* off    = (int*)w; w += (size_t)(NN + 1) * 4;
    int* cursor = (int*)w; w += (size_t)NN * 4;
    int* csr    = (int*)w; w += (size_t)EE * 4;
    int* goff   = (int*)w; w += (size_t)(GG + 1) * 4;
    int* bsum   = (int*)w; w += (size_t)NB * 4;
    int* boff   = (int*)w; w += (size_t)NB * 4;

    const int* srcI = eidx;
    const int* dstI = eidx + EE;

    hipMemcpyAsync(xout,  x_in,  (size_t)NN * DD * 4, hipMemcpyDeviceToDevice, stream);
    hipMemcpyAsync(xglob, xg_in, (size_t)GG * DD * 4, hipMemcpyDeviceToDevice, stream);

    // one-time conversions
    k_f2b<<<cdiv(NN * DD / 4, 256), 256, 0, stream>>>(x_in, xb, NN * DD / 4);
    k_wcvt<<<cdiv(WC1 + WC2 + WC3, 256), 256, 0, stream>>>(Wm, Wa, Wf, Wm_b, Wa_b, Wf_b);

    // CSR by dst (once per call; reused across steps)
    hipMemsetAsync(deg, 0, (size_t)NN * 4, stream);
    k_count<<<cdiv(EE, 256), 256, 0, stream>>>(dstI, deg);
    k_scan1<<<NB, 256, 0, stream>>>(deg, off, bsum);
    k_scan2<<<1, 256, 0, stream>>>(bsum, boff, off);
    k_scan3<<<NB, 256, 0, stream>>>(boff, off, cursor);
    k_fill<<<cdiv(EE, 256), 256, 0, stream>>>(srcI, dstI, cursor, csr);
    k_goff<<<cdiv(NN, 256), 256, 0, stream>>>(batch, goff);

    const int gemmGrid = cdiv(NN, 32);            // 1563
    const int aggGrid  = cdiv(NN * 64, 256);      // 12500

    // msg_0 = bf16(leaky(x @ Wm[0]^T + bm[0]))
    k_mfma<128, false, false, false, false><<<gemmGrid, 256, 0, stream>>>(
        xb, nullptr, Wm_b, bm, nullptr, nullptr, yb, nullptr, nullptr, nullptr, nullptr, nullptr, nullptr);

    for (int i = 0; i < STEPS; ++i) {
        const float* bai = ba + (size_t)i * DD;
        const unsigned short* Wai = Wa_b + (size_t)i * DD * 2 * DD;
        const float* Wgi = Wg + (size_t)i * DD;
        const float* bgi = bg + (size_t)i;
        const unsigned short* Wfi = Wf_b + (size_t)i * DD * DD;
        const float* bfi = bf + (size_t)i * DD;
        const float* Wti = Wt + (size_t)i * DD * 2 * DD;
        const float* bti = bt + (size_t)i * DD;

        // aggb[n] = max over in-edges of yb[src] (exact in bf16)
        k_aggmax<<<aggGrid, 256, 0, stream>>>(yb, off, csr, aggb);
        // x = leaky([x, agg] @ Wa^T + ba) + x ; writes f32 xout, bf16 xb, fused efac=exp(gate)
        k_mfma<256, true, true, true, false><<<gemmGrid, 256, 0, stream>>>(
            xb, aggb, Wai, bai, nullptr, nullptr, xb, nullptr, xout, xout, Wgi, bgi, efac);
        if (i < STEPS - 1) {
            // fused: feat_i -> featb, msg_{i+1} -> yb (both read x_{i+1})
            const unsigned short* Wmn = Wm_b + (size_t)(i + 1) * DD * DD;
            const float* bmn = bm + (size_t)(i + 1) * DD;
            k_mfma<128, false, false, false, true><<<gemmGrid, 256, 0, stream>>>(
                xb, nullptr, Wfi, bfi, Wmn, bmn, featb, yb, nullptr, nullptr, nullptr, nullptr, nullptr);
        } else {
            k_mfma<128, false, false, false, false><<<gemmGrid, 256, 0, stream>>>(
                xb, nullptr, Wfi, bfi, nullptr, nullptr, featb, nullptr, nullptr, nullptr, nullptr, nullptr, nullptr);
        }
        // xg partials (+ efac partials) and global transform
        k_xgpart<<<GG * XP, 128, 0, stream>>>(efac, featb, goff, part, parte);
        k_gtrans<<<GG, 128, 0, stream>>>(part, parte, Wti, bti, xglob);
    }
}

// Round 13
// 529.157 us; speedup vs baseline: 1.4309x; 1.0511x over previous
//
#include <hip/hip_runtime.h>
#include <hip/hip_bf16.h>

#define NN 50000
#define EE 640000
#define DD 128
#define GG 64
#define STEPS 4
#define XP 64
#define NB 196   // cdiv(NN,256) scan blocks

static inline int cdiv(int a, int b) { return (a + b - 1) / b; }

typedef __attribute__((ext_vector_type(8))) short bf16x8;
typedef __attribute__((ext_vector_type(4))) float f32x4;

__device__ __forceinline__ float lk(float z) { return z >= 0.f ? z : 0.01f * z; }
__device__ __forceinline__ float b2f(short b) { return __uint_as_float(((unsigned)(unsigned short)b) << 16); }
__device__ __forceinline__ unsigned short f2b(float f) {
    unsigned u = __float_as_uint(f);
    return (unsigned short)((u + 0x7FFFu + ((u >> 16) & 1u)) >> 16);   // RNE
}

// ---------------- fp32 -> bf16 conversion (vec4) ----------------
__global__ void k_f2b(const float* __restrict__ in, unsigned short* __restrict__ out, int n4) {
    int i = blockIdx.x * blockDim.x + threadIdx.x;
    if (i < n4) {
        float4 v = reinterpret_cast<const float4*>(in)[i];
        ushort4 o;
        o.x = f2b(v.x); o.y = f2b(v.y); o.z = f2b(v.z); o.w = f2b(v.w);
        reinterpret_cast<ushort4*>(out)[i] = o;
    }
}

// fused weight conversion: Wm | Wa | Wf segments (vec4 units)
#define WC1 (STEPS * DD * DD / 4)
#define WC2 (STEPS * DD * 2 * DD / 4)
#define WC3 (STEPS * DD * DD / 4)
__global__ void k_wcvt(const float* __restrict__ Wm, const float* __restrict__ Wa, const float* __restrict__ Wf,
                       unsigned short* __restrict__ Wm_b, unsigned short* __restrict__ Wa_b,
                       unsigned short* __restrict__ Wf_b) {
    int i = blockIdx.x * blockDim.x + threadIdx.x;
    const float* src; unsigned short* dst; int j = i;
    if (j < WC1) { src = Wm; dst = Wm_b; }
    else {
        j -= WC1;
        if (j < WC2) { src = Wa; dst = Wa_b; }
        else {
            j -= WC2;
            if (j >= WC3) return;
            src = Wf; dst = Wf_b;
        }
    }
    float4 v = reinterpret_cast<const float4*>(src)[j];
    ushort4 o;
    o.x = f2b(v.x); o.y = f2b(v.y); o.z = f2b(v.z); o.w = f2b(v.w);
    reinterpret_cast<ushort4*>(dst)[j] = o;
}

// ---------------- CSR build ----------------
__global__ void k_count(const int* __restrict__ dst, int* __restrict__ deg) {
    int e = blockIdx.x * blockDim.x + threadIdx.x;
    if (e < EE) atomicAdd(&deg[dst[e]], 1);
}

__global__ __launch_bounds__(256) void k_scan1(const int* __restrict__ deg, int* __restrict__ off,
                                               int* __restrict__ bsum) {
    __shared__ int ws[4];
    int tid = threadIdx.x, lane = tid & 63, wv = tid >> 6;
    int i = blockIdx.x * 256 + tid;
    int v = (i < NN) ? deg[i] : 0;
    int x = v;
    #pragma unroll
    for (int o = 1; o < 64; o <<= 1) { int t = __shfl_up(x, o); if (lane >= o) x += t; }
    if (lane == 63) ws[wv] = x;
    __syncthreads();
    int wbase = 0;
    #pragma unroll
    for (int p = 0; p < 3; ++p) if (p < wv) wbase += ws[p];
    if (i < NN) off[i] = wbase + x - v;
    if (tid == 255) bsum[blockIdx.x] = wbase + x;
}

__global__ __launch_bounds__(256) void k_scan2(const int* __restrict__ bsum, int* __restrict__ boff,
                                               int* __restrict__ off) {
    __shared__ int ws[4];
    int tid = threadIdx.x, lane = tid & 63, wv = tid >> 6;
    int v = (tid < NB) ? bsum[tid] : 0;
    int x = v;
    #pragma unroll
    for (int o = 1; o < 64; o <<= 1) { int t = __shfl_up(x, o); if (lane >= o) x += t; }
    if (lane == 63) ws[wv] = x;
    __syncthreads();
    int wbase = 0;
    #pragma unroll
    for (int p = 0; p < 3; ++p) if (p < wv) wbase += ws[p];
    if (tid < NB) boff[tid] = wbase + x - v;
    if (tid == 255) off[NN] = wbase + x;
}

__global__ __launch_bounds__(256) void k_scan3(const int* __restrict__ boff, int* __restrict__ off,
                                               int* __restrict__ cursor) {
    int i = blockIdx.x * 256 + threadIdx.x;
    if (i < NN) {
        int o = off[i] + boff[blockIdx.x];
        off[i] = o;
        cursor[i] = o;
    }
}

__global__ void k_fill(const int* __restrict__ src, const int* __restrict__ dst,
                       int* __restrict__ cursor, int* __restrict__ csr) {
    int e = blockIdx.x * blockDim.x + threadIdx.x;
    if (e < EE) {
        int d = dst[e];
        int p = atomicAdd(&cursor[d], 1);
        csr[p] = src[e];
    }
}

__global__ void k_goff(const int* __restrict__ batch, int* __restrict__ goff) {
    int i = blockIdx.x * blockDim.x + threadIdx.x;
    if (i >= NN) return;
    int b = batch[i];
    int prev = (i == 0) ? -1 : batch[i - 1];
    for (int g = prev + 1; g <= b; ++g) goff[g] = i;
    if (i == NN - 1) for (int g = b + 1; g <= GG; ++g) goff[g] = NN;
}

// ---------------- simple MFMA GEMM (msg_0): Yb = bf16(leaky(X @ W^T + b)) ----------------
// 32-row tile, col-split waves; MFMA 16x16x32; LDS-staged epilogue.
__global__ __launch_bounds__(256) void k_g128(
    const unsigned short* __restrict__ Xb, const unsigned short* __restrict__ W1,
    const float* __restrict__ b1, unsigned short* __restrict__ Yb1)
{
    __shared__ float sY[32 * 128];
    const int tid = threadIdx.x;
    const int wv = tid >> 6, lane = tid & 63;
    const int lo = lane & 15, hi = lane >> 4;
    const int rw = wv >> 1, cw = wv & 1;
    const int n0 = blockIdx.x * 32;
    const int arow = n0 + rw * 16 + lo;
    const bool rvalid = arow < NN;

    bf16x8 a[4];
    #pragma unroll
    for (int kc = 0; kc < 4; ++kc) {
        const int k = kc * 32 + hi * 8;
        a[kc] = rvalid ? *reinterpret_cast<const bf16x8*>(&Xb[(size_t)arow * 128 + k]) : (bf16x8)(short)0;
    }
    f32x4 acc[4];
    #pragma unroll
    for (int t = 0; t < 4; ++t) acc[t] = (f32x4){0.f,0.f,0.f,0.f};
    #pragma unroll
    for (int kc = 0; kc < 4; ++kc) {
        const int k = kc * 32 + hi * 8;
        #pragma unroll
        for (int t = 0; t < 4; ++t) {
            const int o = cw * 64 + t * 16 + lo;
            bf16x8 bv = *reinterpret_cast<const bf16x8*>(&W1[(size_t)o * 128 + k]);
            acc[t] = __builtin_amdgcn_mfma_f32_16x16x32_bf16(a[kc], bv, acc[t], 0, 0, 0);
        }
    }
    const int lrow = rw * 16 + hi * 4;
    const int swz = (hi & 1) << 4;
    #pragma unroll
    for (int t = 0; t < 4; ++t) {
        const int oc = cw * 64 + t * 16 + lo;
        const int col = oc ^ swz;
        const float bc = b1[oc];
        #pragma unroll
        for (int r = 0; r < 4; ++r) sY[(lrow + r) * 128 + col] = lk(acc[t][r] + bc);
    }
    __syncthreads();
    #pragma unroll
    for (int it = 0; it < 2; ++it) {
        const int idx = it * 256 + tid;
        const int row = idx >> 4, ub = (idx & 15) * 8;
        const int n = n0 + row;
        if (n < NN) {
            const int ubx = ub ^ (((row >> 2) & 1) << 4);
            bf16x8 ob;
            #pragma unroll
            for (int j = 0; j < 8; ++j) ob[j] = (short)f2b(sY[row * 128 + ubx + j]);
            *reinterpret_cast<bf16x8*>(&Yb1[(size_t)n * 128 + ub]) = ob;
        }
    }
}

// ---------------- MEGA step kernel ----------------
// x_new = leaky([x,agg]@Wa^T + ba) + resid  -> xout(f32), xb(bf16), efac=exp(gate)
// then (block-locally, x_new from LDS): feat = leaky(x_new@Wf^T+bf) -> featb
//                          and if MSG: msg = leaky(x_new@Wm2^T+bm2) -> ybm
// sXn: [32][136] bf16 (pad 8 elems => 272B row stride, 16B-aligned, 2-way banks only).
template<bool MSG>
__global__ __launch_bounds__(256) void k_mega(
    const unsigned short* __restrict__ Xb, const unsigned short* __restrict__ Ab,
    const unsigned short* __restrict__ Wa, const float* __restrict__ ba,
    const float* __restrict__ resid,
    const float* __restrict__ wgf, const float* __restrict__ bgp,
    const unsigned short* __restrict__ Wf, const float* __restrict__ bfp,
    const unsigned short* __restrict__ Wm2, const float* __restrict__ bm2,
    float* __restrict__ Yf, unsigned short* __restrict__ Xbout,
    float* __restrict__ efac, unsigned short* __restrict__ featb,
    unsigned short* __restrict__ ybm)
{
    __shared__ float sY[32 * 128];
    __shared__ unsigned short sXn[32 * 136];
    const int tid = threadIdx.x;
    const int wv = tid >> 6, lane = tid & 63;
    const int lo = lane & 15, hi = lane >> 4;
    const int rw = wv >> 1, cw = wv & 1;
    const int n0 = blockIdx.x * 32;
    const int arow = n0 + rw * 16 + lo;
    const bool rvalid = arow < NN;

    // phase 1: prefetch A chunks (x | agg), all loads in flight
    bf16x8 a[8];
    #pragma unroll
    for (int kc = 0; kc < 8; ++kc) {
        const int k = kc * 32 + hi * 8;
        if (rvalid) {
            const unsigned short* base = (kc < 4) ? &Xb[(size_t)arow * 128 + k]
                                                  : &Ab[(size_t)arow * 128 + (k - 128)];
            a[kc] = *reinterpret_cast<const bf16x8*>(base);
        } else a[kc] = (bf16x8)(short)0;
    }

    // phase 2: K=256 MFMA
    f32x4 acc1[4];
    #pragma unroll
    for (int t = 0; t < 4; ++t) acc1[t] = (f32x4){0.f,0.f,0.f,0.f};
    #pragma unroll
    for (int kc = 0; kc < 8; ++kc) {
        const int k = kc * 32 + hi * 8;
        #pragma unroll
        for (int t = 0; t < 4; ++t) {
            const int o = cw * 64 + t * 16 + lo;
            bf16x8 bv = *reinterpret_cast<const bf16x8*>(&Wa[(size_t)o * 256 + k]);
            acc1[t] = __builtin_amdgcn_mfma_f32_16x16x32_bf16(a[kc], bv, acc1[t], 0, 0, 0);
        }
    }

    // phase 3: stage leaky(acc1 + ba), col XOR-swizzled
    const int lrow = rw * 16 + hi * 4;
    const int swz = (hi & 1) << 4;
    #pragma unroll
    for (int t = 0; t < 4; ++t) {
        const int oc = cw * 64 + t * 16 + lo;
        const int col = oc ^ swz;
        const float bc = ba[oc];
        #pragma unroll
        for (int r = 0; r < 4; ++r) sY[(lrow + r) * 128 + col] = lk(acc1[t][r] + bc);
    }
    __syncthreads();

    // phase 4: linear epilogue: v = sY + resid; write xout/xb; gate->efac; stage sXn
    {
        const float bg0 = bgp[0];
        #pragma unroll
        for (int it = 0; it < 4; ++it) {
            const int idx = it * 256 + tid;
            const int row = idx >> 5, u4 = (idx & 31) * 4;
            const int n = n0 + row;
            const bool valid = n < NN;
            const int ux = u4 ^ (((row >> 2) & 1) << 4);
            float4 v = *reinterpret_cast<const float4*>(&sY[row * 128 + ux]);
            if (valid) {
                float4 rsd = *reinterpret_cast<const float4*>(&resid[(size_t)n * 128 + u4]);
                v.x += rsd.x; v.y += rsd.y; v.z += rsd.z; v.w += rsd.w;
                *reinterpret_cast<float4*>(&Yf[(size_t)n * 128 + u4]) = v;
            }
            ushort4 ob;
            ob.x = f2b(v.x); ob.y = f2b(v.y); ob.z = f2b(v.z); ob.w = f2b(v.w);
            if (valid) *reinterpret_cast<ushort4*>(&Xbout[(size_t)n * 128 + u4]) = ob;
            *reinterpret_cast<ushort4*>(&sXn[row * 136 + u4]) = ob;   // x_new bf16 tile
            float4 wg4 = *reinterpret_cast<const float4*>(&wgf[u4]);
            float gs = valid ? (v.x * wg4.x + v.y * wg4.y + v.z * wg4.z + v.w * wg4.w) : 0.f;
            #pragma unroll
            for (int sh = 16; sh > 0; sh >>= 1) gs += __shfl_xor(gs, sh);
            if ((lane & 31) == 0 && valid) efac[n] = __expf(gs + bg0);
        }
    }
    __syncthreads();

    // phase 5: feat (+msg) MFMAs, A from sXn
    bf16x8 a2[4];
    #pragma unroll
    for (int kc = 0; kc < 4; ++kc) {
        const int k = kc * 32 + hi * 8;
        a2[kc] = *reinterpret_cast<const bf16x8*>(&sXn[(rw * 16 + lo) * 136 + k]);
    }
    f32x4 accF[4], accM[4];
    #pragma unroll
    for (int t = 0; t < 4; ++t) { accF[t] = (f32x4){0.f,0.f,0.f,0.f}; accM[t] = (f32x4){0.f,0.f,0.f,0.f}; }
    #pragma unroll
    for (int kc = 0; kc < 4; ++kc) {
        const int k = kc * 32 + hi * 8;
        #pragma unroll
        for (int t = 0; t < 4; ++t) {
            const int o = cw * 64 + t * 16 + lo;
            bf16x8 bv = *reinterpret_cast<const bf16x8*>(&Wf[(size_t)o * 128 + k]);
            accF[t] = __builtin_amdgcn_mfma_f32_16x16x32_bf16(a2[kc], bv, accF[t], 0, 0, 0);
            if (MSG) {
                bf16x8 bv2 = *reinterpret_cast<const bf16x8*>(&Wm2[(size_t)o * 128 + k]);
                accM[t] = __builtin_amdgcn_mfma_f32_16x16x32_bf16(a2[kc], bv2, accM[t], 0, 0, 0);
            }
        }
    }
    __syncthreads();   // all phase-4 sY reads complete (they were, before the last barrier)

    // phase 6/7: stage + store feat
    #pragma unroll
    for (int t = 0; t < 4; ++t) {
        const int oc = cw * 64 + t * 16 + lo;
        const int col = oc ^ swz;
        const float bc = bfp[oc];
        #pragma unroll
        for (int r = 0; r < 4; ++r) sY[(lrow + r) * 128 + col] = lk(accF[t][r] + bc);
    }
    __syncthreads();
    #pragma unroll
    for (int it = 0; it < 2; ++it) {
        const int idx = it * 256 + tid;
        const int row = idx >> 4, ub = (idx & 15) * 8;
        const int n = n0 + row;
        if (n < NN) {
            const int ubx = ub ^ (((row >> 2) & 1) << 4);
            bf16x8 ob;
            #pragma unroll
            for (int j = 0; j < 8; ++j) ob[j] = (short)f2b(sY[row * 128 + ubx + j]);
            *reinterpret_cast<bf16x8*>(&featb[(size_t)n * 128 + ub]) = ob;
        }
    }

    if (MSG) {
        __syncthreads();
        #pragma unroll
        for (int t = 0; t < 4; ++t) {
            const int oc = cw * 64 + t * 16 + lo;
            const int col = oc ^ swz;
            const float bc = bm2[oc];
            #pragma unroll
            for (int r = 0; r < 4; ++r) sY[(lrow + r) * 128 + col] = lk(accM[t][r] + bc);
        }
        __syncthreads();
        #pragma unroll
        for (int it = 0; it < 2; ++it) {
            const int idx = it * 256 + tid;
            const int row = idx >> 4, ub = (idx & 15) * 8;
            const int n = n0 + row;
            if (n < NN) {
                const int ubx = ub ^ (((row >> 2) & 1) << 4);
                bf16x8 ob;
                #pragma unroll
                for (int j = 0; j < 8; ++j) ob[j] = (short)f2b(sY[row * 128 + ubx + j]);
                *reinterpret_cast<bf16x8*>(&ybm[(size_t)n * 128 + ub]) = ob;
            }
        }
    }
}

// ---------------- scatter-max via CSR: one wave per node, 8 edges/iter, bf16 ----------------
__global__ __launch_bounds__(256) void k_aggmax(const unsigned short* __restrict__ yb,
                                                const int* __restrict__ off,
                                                const int* __restrict__ csr,
                                                unsigned short* __restrict__ aggb) {
    int gtid = blockIdx.x * blockDim.x + threadIdx.x;
    int node = gtid >> 6;
    if (node >= NN) return;
    int lane = threadIdx.x & 63;
    int slot = lane >> 4, c8 = (lane & 15) * 8;
    int b = off[node], e = off[node + 1];
    int deg = e - b;
    float m[8];
    #pragma unroll
    for (int j = 0; j < 8; ++j) m[j] = -3.4e38f;
    if (deg > 0) {
        int T = (deg + 7) >> 3;
        for (int it = 0; it < T; ++it) {
            int p0 = b + it * 8 + slot;
            int p1 = p0 + 4;
            int i0 = csr[p0 < e ? p0 : b];
            int i1 = csr[p1 < e ? p1 : b];
            bf16x8 v0 = *reinterpret_cast<const bf16x8*>(&yb[(size_t)i0 * 128 + c8]);
            bf16x8 v1 = *reinterpret_cast<const bf16x8*>(&yb[(size_t)i1 * 128 + c8]);
            #pragma unroll
            for (int j = 0; j < 8; ++j) m[j] = fmaxf(m[j], fmaxf(b2f(v0[j]), b2f(v1[j])));
        }
    }
    #pragma unroll
    for (int j = 0; j < 8; ++j) m[j] = fmaxf(m[j], __shfl_xor(m[j], 16));
    #pragma unroll
    for (int j = 0; j < 8; ++j) m[j] = fmaxf(m[j], __shfl_xor(m[j], 32));
    if (slot == 0) {
        bf16x8 o;
        #pragma unroll
        for (int j = 0; j < 8; ++j) o[j] = (deg > 0) ? (short)f2b(m[j]) : (short)0;
        *reinterpret_cast<bf16x8*>(&aggb[(size_t)node * 128 + c8]) = o;
    }
}

// ---------------- xg partial sums (+ efac partial sums), deterministic order ----------------
__global__ __launch_bounds__(128) void k_xgpart(const float* __restrict__ efac,
                                                const unsigned short* __restrict__ featb,
                                                const int* __restrict__ goff,
                                                float* __restrict__ part, float* __restrict__ parte) {
    int g = blockIdx.x >> 6, p = blockIdx.x & 63;
    int d = threadIdx.x;
    int b = goff[g], e = goff[g + 1];
    int len = e - b;
    int chunk = (len + XP - 1) / XP;
    int s0 = b + p * chunk;
    int s1 = min(e, s0 + chunk);
    float acc = 0.f, acce = 0.f;
    #pragma unroll 4
    for (int i = s0; i < s1; ++i) {
        float ev = efac[i];
        acce += ev;
        acc += ev * b2f(featb[(size_t)i * 128 + d]);
    }
    part[((size_t)g * XP + p) * 128 + d] = acc;
    if (d == 0) parte[(size_t)g * XP + p] = acce;
}

// ---------------- global transform (combines efac partials -> denom) ----------------
__global__ __launch_bounds__(128) void k_gtrans(const float* __restrict__ part, const float* __restrict__ parte,
                                                const float* __restrict__ Wt, const float* __restrict__ bt,
                                                float* __restrict__ xglob) {
    __shared__ float cat[256];
    int g = blockIdx.x;
    int o = threadIdx.x;
    float xgv = 0.f, se = 0.f;
    #pragma unroll
    for (int p = 0; p < XP; ++p) {
        xgv += part[((size_t)g * XP + p) * 128 + o];
        se  += parte[(size_t)g * XP + p];
    }
    if (se == 0.f) se = 1.f;
    cat[o] = xgv / se;
    cat[128 + o] = xglob[(size_t)g * 128 + o];
    __syncthreads();
    float accv = bt[o];
    const float4* w4 = reinterpret_cast<const float4*>(&Wt[(size_t)o * 256]);
    #pragma unroll 8
    for (int k4 = 0; k4 < 64; ++k4) {
        float4 wv = w4[k4];
        accv += cat[4 * k4 + 0] * wv.x + cat[4 * k4 + 1] * wv.y + cat[4 * k4 + 2] * wv.z + cat[4 * k4 + 3] * wv.w;
    }
    float outv = lk(accv) + cat[128 + o];
    xglob[(size_t)g * 128 + o] = outv;
}

extern "C" void kernel_launch(void* const* d_in, const int* in_sizes, int n_in,
                              void* d_out, int out_size, void* d_ws, size_t ws_size,
                              hipStream_t stream) {
    const float* x_in  = (const float*)d_in[0];
    const float* xg_in = (const float*)d_in[1];
    const float* Wm = (const float*)d_in[3];
    const float* bm = (const float*)d_in[4];
    const float* Wa = (const float*)d_in[5];
    const float* ba = (const float*)d_in[6];
    const float* Wg = (const float*)d_in[7];
    const float* bg = (const float*)d_in[8];
    const float* Wf = (const float*)d_in[9];
    const float* bf = (const float*)d_in[10];
    const float* Wt = (const float*)d_in[11];
    const float* bt = (const float*)d_in[12];
    const int* eidx  = (const int*)d_in[13];
    const int* batch = (const int*)d_in[14];

    float* xout  = (float*)d_out;                 // [N,128] evolving x (f32 carry)
    float* xglob = xout + (size_t)NN * DD;        // [G,128] evolving x_global

    char* w = (char*)d_ws;
    unsigned short* yb    = (unsigned short*)w; w += (size_t)NN * DD * 2;  // msg bf16
    unsigned short* featb = (unsigned short*)w; w += (size_t)NN * DD * 2;  // feat bf16
    unsigned short* aggb  = (unsigned short*)w; w += (size_t)NN * DD * 2;
    unsigned short* xb    = (unsigned short*)w; w += (size_t)NN * DD * 2;  // bf16 shadow of x
    unsigned short* Wm_b  = (unsigned short*)w; w += (size_t)STEPS * DD * DD * 2;
    unsigned short* Wa_b  = (unsigned short*)w; w += (size_t)STEPS * DD * 2 * DD * 2;
    unsigned short* Wf_b  = (unsigned short*)w; w += (size_t)STEPS * DD * DD * 2;
    float* efac   = (float*)w; w += (size_t)NN * 4;
    float* part   = (float*)w; w += (size_t)GG * XP * DD * 4;
    float* parte  = (float*)w; w += (size_t)GG * XP * 4;
    int* deg    = (int*)w; w += (size_t)(NN + 1) * 4;
    int* off    = (int*)w; w += (size_t)(NN + 1) * 4;
    int* cursor = (int*)w; w += (size_t)NN * 4;
    int* csr    = (int*)w; w += (size_t)EE * 4;
    int* goff   = (int*)w; w += (size_t)(GG + 1) * 4;
    int* bsum   = (int*)w; w += (size_t)NB * 4;
    int* boff   = (int*)w; w += (size_t)NB * 4;

    const int* srcI = eidx;
    const int* dstI = eidx + EE;

    // xglob init (xout fully written by step-0 mega; resid for step 0 reads x_in directly)
    hipMemcpyAsync(xglob, xg_in, (size_t)GG * DD * 4, hipMemcpyDeviceToDevice, stream);

    // one-time conversions
    k_f2b<<<cdiv(NN * DD / 4, 256), 256, 0, stream>>>(x_in, xb, NN * DD / 4);
    k_wcvt<<<cdiv(WC1 + WC2 + WC3, 256), 256, 0, stream>>>(Wm, Wa, Wf, Wm_b, Wa_b, Wf_b);

    // CSR by dst (once per call; reused across steps)
    hipMemsetAsync(deg, 0, (size_t)NN * 4, stream);
    k_count<<<cdiv(EE, 256), 256, 0, stream>>>(dstI, deg);
    k_scan1<<<NB, 256, 0, stream>>>(deg, off, bsum);
    k_scan2<<<1, 256, 0, stream>>>(bsum, boff, off);
    k_scan3<<<NB, 256, 0, stream>>>(boff, off, cursor);
    k_fill<<<cdiv(EE, 256), 256, 0, stream>>>(srcI, dstI, cursor, csr);
    k_goff<<<cdiv(NN, 256), 256, 0, stream>>>(batch, goff);

    const int gemmGrid = cdiv(NN, 32);            // 1563
    const int aggGrid  = cdiv(NN * 64, 256);      // 12500

    // msg_0 = bf16(leaky(x @ Wm[0]^T + bm[0]))
    k_g128<<<gemmGrid, 256, 0, stream>>>(xb, Wm_b, bm, yb);

    for (int i = 0; i < STEPS; ++i) {
        const float* bai = ba + (size_t)i * DD;
        const unsigned short* Wai = Wa_b + (size_t)i * DD * 2 * DD;
        const float* Wgi = Wg + (size_t)i * DD;
        const float* bgi = bg + (size_t)i;
        const unsigned short* Wfi = Wf_b + (size_t)i * DD * DD;
        const float* bfi = bf + (size_t)i * DD;
        const float* Wti = Wt + (size_t)i * DD * 2 * DD;
        const float* bti = bt + (size_t)i * DD;
        const float* residp = (i == 0) ? x_in : xout;

        // aggb[n] = max over in-edges of yb[src]
        k_aggmax<<<aggGrid, 256, 0, stream>>>(yb, off, csr, aggb);
        // mega: x_new (xout, xb), efac=exp(gate), feat -> featb, msg_{i+1} -> yb
        if (i < STEPS - 1) {
            const unsigned short* Wmn = Wm_b + (size_t)(i + 1) * DD * DD;
            const float* bmn = bm + (size_t)(i + 1) * DD;
            k_mega<true><<<gemmGrid, 256, 0, stream>>>(
                xb, aggb, Wai, bai, residp, Wgi, bgi, Wfi, bfi, Wmn, bmn,
                xout, xb, efac, featb, yb);
        } else {
            k_mega<false><<<gemmGrid, 256, 0, stream>>>(
                xb, aggb, Wai, bai, residp, Wgi, bgi, Wfi, bfi, nullptr, nullptr,
                xout, xb, efac, featb, nullptr);
        }
        // xg partials (+ efac partials) and global transform
        k_xgpart<<<GG * XP, 128, 0, stream>>>(efac, featb, goff, part, parte);
        k_gtrans<<<GG, 128, 0, stream>>>(part, parte, Wti, bti, xglob);
    }
}

// Round 14
// 517.674 us; speedup vs baseline: 1.4627x; 1.0222x over previous
//
#include <hip/hip_runtime.h>
#include <hip/hip_bf16.h>

#define NN 50000
#define EE 640000
#define DD 128
#define GG 64
#define STEPS 4
#define XP 64
#define NB 196   // cdiv(NN,256) scan blocks

static inline int cdiv(int a, int b) { return (a + b - 1) / b; }

typedef __attribute__((ext_vector_type(8))) short bf16x8;
typedef __attribute__((ext_vector_type(4))) float f32x4;

__device__ __forceinline__ float lk(float z) { return z >= 0.f ? z : 0.01f * z; }
__device__ __forceinline__ float b2f(short b) { return __uint_as_float(((unsigned)(unsigned short)b) << 16); }
__device__ __forceinline__ float b2fu(unsigned short b) { return __uint_as_float(((unsigned)b) << 16); }
__device__ __forceinline__ unsigned short f2b(float f) {
    unsigned u = __float_as_uint(f);
    return (unsigned short)((u + 0x7FFFu + ((u >> 16) & 1u)) >> 16);   // RNE
}

// ---------------- fp32 -> bf16 conversion (vec4) ----------------
__global__ void k_f2b(const float* __restrict__ in, unsigned short* __restrict__ out, int n4) {
    int i = blockIdx.x * blockDim.x + threadIdx.x;
    if (i < n4) {
        float4 v = reinterpret_cast<const float4*>(in)[i];
        ushort4 o;
        o.x = f2b(v.x); o.y = f2b(v.y); o.z = f2b(v.z); o.w = f2b(v.w);
        reinterpret_cast<ushort4*>(out)[i] = o;
    }
}

// fused weight conversion: Wm | Wa | Wf segments (vec4 units)
#define WC1 (STEPS * DD * DD / 4)
#define WC2 (STEPS * DD * 2 * DD / 4)
#define WC3 (STEPS * DD * DD / 4)
__global__ void k_wcvt(const float* __restrict__ Wm, const float* __restrict__ Wa, const float* __restrict__ Wf,
                       unsigned short* __restrict__ Wm_b, unsigned short* __restrict__ Wa_b,
                       unsigned short* __restrict__ Wf_b) {
    int i = blockIdx.x * blockDim.x + threadIdx.x;
    const float* src; unsigned short* dst; int j = i;
    if (j < WC1) { src = Wm; dst = Wm_b; }
    else {
        j -= WC1;
        if (j < WC2) { src = Wa; dst = Wa_b; }
        else {
            j -= WC2;
            if (j >= WC3) return;
            src = Wf; dst = Wf_b;
        }
    }
    float4 v = reinterpret_cast<const float4*>(src)[j];
    ushort4 o;
    o.x = f2b(v.x); o.y = f2b(v.y); o.z = f2b(v.z); o.w = f2b(v.w);
    reinterpret_cast<ushort4*>(dst)[j] = o;
}

// ---------------- CSR build ----------------
__global__ void k_count(const int* __restrict__ dst, int* __restrict__ deg) {
    int e = blockIdx.x * blockDim.x + threadIdx.x;
    if (e < EE) atomicAdd(&deg[dst[e]], 1);
}

__global__ __launch_bounds__(256) void k_scan1(const int* __restrict__ deg, int* __restrict__ off,
                                               int* __restrict__ bsum) {
    __shared__ int ws[4];
    int tid = threadIdx.x, lane = tid & 63, wv = tid >> 6;
    int i = blockIdx.x * 256 + tid;
    int v = (i < NN) ? deg[i] : 0;
    int x = v;
    #pragma unroll
    for (int o = 1; o < 64; o <<= 1) { int t = __shfl_up(x, o); if (lane >= o) x += t; }
    if (lane == 63) ws[wv] = x;
    __syncthreads();
    int wbase = 0;
    #pragma unroll
    for (int p = 0; p < 3; ++p) if (p < wv) wbase += ws[p];
    if (i < NN) off[i] = wbase + x - v;
    if (tid == 255) bsum[blockIdx.x] = wbase + x;
}

__global__ __launch_bounds__(256) void k_scan2(const int* __restrict__ bsum, int* __restrict__ boff,
                                               int* __restrict__ off) {
    __shared__ int ws[4];
    int tid = threadIdx.x, lane = tid & 63, wv = tid >> 6;
    int v = (tid < NB) ? bsum[tid] : 0;
    int x = v;
    #pragma unroll
    for (int o = 1; o < 64; o <<= 1) { int t = __shfl_up(x, o); if (lane >= o) x += t; }
    if (lane == 63) ws[wv] = x;
    __syncthreads();
    int wbase = 0;
    #pragma unroll
    for (int p = 0; p < 3; ++p) if (p < wv) wbase += ws[p];
    if (tid < NB) boff[tid] = wbase + x - v;
    if (tid == 255) off[NN] = wbase + x;
}

__global__ __launch_bounds__(256) void k_scan3(const int* __restrict__ boff, int* __restrict__ off,
                                               int* __restrict__ cursor) {
    int i = blockIdx.x * 256 + threadIdx.x;
    if (i < NN) {
        int o = off[i] + boff[blockIdx.x];
        off[i] = o;
        cursor[i] = o;
    }
}

__global__ void k_fill(const int* __restrict__ src, const int* __restrict__ dst,
                       int* __restrict__ cursor, int* __restrict__ csr) {
    int e = blockIdx.x * blockDim.x + threadIdx.x;
    if (e < EE) {
        int d = dst[e];
        int p = atomicAdd(&cursor[d], 1);
        csr[p] = src[e];
    }
}

__global__ void k_goff(const int* __restrict__ batch, int* __restrict__ goff) {
    int i = blockIdx.x * blockDim.x + threadIdx.x;
    if (i >= NN) return;
    int b = batch[i];
    int prev = (i == 0) ? -1 : batch[i - 1];
    for (int g = prev + 1; g <= b; ++g) goff[g] = i;
    if (i == NN - 1) for (int g = b + 1; g <= GG; ++g) goff[g] = NN;
}

// ---------------- simple MFMA GEMM (msg_0): Yb = bf16(leaky(X @ W^T + b)) ----------------
__global__ __launch_bounds__(256) void k_g128(
    const unsigned short* __restrict__ Xb, const unsigned short* __restrict__ W1,
    const float* __restrict__ b1, unsigned short* __restrict__ Yb1)
{
    __shared__ float sY[32 * 128];
    const int tid = threadIdx.x;
    const int wv = tid >> 6, lane = tid & 63;
    const int lo = lane & 15, hi = lane >> 4;
    const int rw = wv >> 1, cw = wv & 1;
    const int n0 = blockIdx.x * 32;
    const int arow = n0 + rw * 16 + lo;
    const bool rvalid = arow < NN;

    bf16x8 a[4];
    #pragma unroll
    for (int kc = 0; kc < 4; ++kc) {
        const int k = kc * 32 + hi * 8;
        a[kc] = rvalid ? *reinterpret_cast<const bf16x8*>(&Xb[(size_t)arow * 128 + k]) : (bf16x8)(short)0;
    }
    f32x4 acc[4];
    #pragma unroll
    for (int t = 0; t < 4; ++t) acc[t] = (f32x4){0.f,0.f,0.f,0.f};
    #pragma unroll
    for (int kc = 0; kc < 4; ++kc) {
        const int k = kc * 32 + hi * 8;
        #pragma unroll
        for (int t = 0; t < 4; ++t) {
            const int o = cw * 64 + t * 16 + lo;
            bf16x8 bv = *reinterpret_cast<const bf16x8*>(&W1[(size_t)o * 128 + k]);
            acc[t] = __builtin_amdgcn_mfma_f32_16x16x32_bf16(a[kc], bv, acc[t], 0, 0, 0);
        }
    }
    const int lrow = rw * 16 + hi * 4;
    const int swz = (hi & 1) << 4;
    #pragma unroll
    for (int t = 0; t < 4; ++t) {
        const int oc = cw * 64 + t * 16 + lo;
        const int col = oc ^ swz;
        const float bc = b1[oc];
        #pragma unroll
        for (int r = 0; r < 4; ++r) sY[(lrow + r) * 128 + col] = lk(acc[t][r] + bc);
    }
    __syncthreads();
    #pragma unroll
    for (int it = 0; it < 2; ++it) {
        const int idx = it * 256 + tid;
        const int row = idx >> 4, ub = (idx & 15) * 8;
        const int n = n0 + row;
        if (n < NN) {
            const int ubx = ub ^ (((row >> 2) & 1) << 4);
            bf16x8 ob;
            #pragma unroll
            for (int j = 0; j < 8; ++j) ob[j] = (short)f2b(sY[row * 128 + ubx + j]);
            *reinterpret_cast<bf16x8*>(&Yb1[(size_t)n * 128 + ub]) = ob;
        }
    }
}

// ---------------- MEGA step kernel (bf16 carry) ----------------
// x_new = leaky([x,agg]@Wa^T + ba) + b2f(xb_old)  -> xb(bf16) [or xout f32 if LAST], efac=exp(gate)
// then (block-locally, x_new bf16 from LDS): feat -> featb; if MSG: msg -> ybm.
// In-place xb RMW is safe: per-thread element read precedes write; blocks own disjoint rows;
// phase-1 A reads precede the phase-3 barrier which precedes phase-4 writes.
template<bool MSG, bool LAST>
__global__ __launch_bounds__(256) void k_mega(
    const unsigned short* __restrict__ Xb, const unsigned short* __restrict__ Ab,
    const unsigned short* __restrict__ Wa, const float* __restrict__ ba,
    const float* __restrict__ wgf, const float* __restrict__ bgp,
    const unsigned short* __restrict__ Wf, const float* __restrict__ bfp,
    const unsigned short* __restrict__ Wm2, const float* __restrict__ bm2,
    float* __restrict__ Yf, unsigned short* __restrict__ Xbout,
    float* __restrict__ efac, unsigned short* __restrict__ featb,
    unsigned short* __restrict__ ybm)
{
    __shared__ float sY[32 * 128];
    __shared__ unsigned short sXn[32 * 136];
    const int tid = threadIdx.x;
    const int wv = tid >> 6, lane = tid & 63;
    const int lo = lane & 15, hi = lane >> 4;
    const int rw = wv >> 1, cw = wv & 1;
    const int n0 = blockIdx.x * 32;
    const int arow = n0 + rw * 16 + lo;
    const bool rvalid = arow < NN;

    // phase 1: prefetch A chunks (x | agg), all loads in flight
    bf16x8 a[8];
    #pragma unroll
    for (int kc = 0; kc < 8; ++kc) {
        const int k = kc * 32 + hi * 8;
        if (rvalid) {
            const unsigned short* base = (kc < 4) ? &Xb[(size_t)arow * 128 + k]
                                                  : &Ab[(size_t)arow * 128 + (k - 128)];
            a[kc] = *reinterpret_cast<const bf16x8*>(base);
        } else a[kc] = (bf16x8)(short)0;
    }

    // phase 2: K=256 MFMA
    f32x4 acc1[4];
    #pragma unroll
    for (int t = 0; t < 4; ++t) acc1[t] = (f32x4){0.f,0.f,0.f,0.f};
    #pragma unroll
    for (int kc = 0; kc < 8; ++kc) {
        const int k = kc * 32 + hi * 8;
        #pragma unroll
        for (int t = 0; t < 4; ++t) {
            const int o = cw * 64 + t * 16 + lo;
            bf16x8 bv = *reinterpret_cast<const bf16x8*>(&Wa[(size_t)o * 256 + k]);
            acc1[t] = __builtin_amdgcn_mfma_f32_16x16x32_bf16(a[kc], bv, acc1[t], 0, 0, 0);
        }
    }

    // phase 3: stage leaky(acc1 + ba), col XOR-swizzled
    const int lrow = rw * 16 + hi * 4;
    const int swz = (hi & 1) << 4;
    #pragma unroll
    for (int t = 0; t < 4; ++t) {
        const int oc = cw * 64 + t * 16 + lo;
        const int col = oc ^ swz;
        const float bc = ba[oc];
        #pragma unroll
        for (int r = 0; r < 4; ++r) sY[(lrow + r) * 128 + col] = lk(acc1[t][r] + bc);
    }
    __syncthreads();

    // phase 4: v = sY + b2f(xb_old); write xb (or xout f32 if LAST); gate->efac; stage sXn
    {
        const float bg0 = bgp[0];
        #pragma unroll
        for (int it = 0; it < 4; ++it) {
            const int idx = it * 256 + tid;
            const int row = idx >> 5, u4 = (idx & 31) * 4;
            const int n = n0 + row;
            const bool valid = n < NN;
            const int ux = u4 ^ (((row >> 2) & 1) << 4);
            float4 v = *reinterpret_cast<const float4*>(&sY[row * 128 + ux]);
            if (valid) {
                ushort4 rb = *reinterpret_cast<const ushort4*>(&Xb[(size_t)n * 128 + u4]);
                v.x += b2fu(rb.x); v.y += b2fu(rb.y); v.z += b2fu(rb.z); v.w += b2fu(rb.w);
            }
            ushort4 ob;
            ob.x = f2b(v.x); ob.y = f2b(v.y); ob.z = f2b(v.z); ob.w = f2b(v.w);
            if (valid) {
                if (LAST) *reinterpret_cast<float4*>(&Yf[(size_t)n * 128 + u4]) = v;
                else      *reinterpret_cast<ushort4*>(&Xbout[(size_t)n * 128 + u4]) = ob;
            }
            *reinterpret_cast<ushort4*>(&sXn[row * 136 + u4]) = ob;   // x_new bf16 tile
            float4 wg4 = *reinterpret_cast<const float4*>(&wgf[u4]);
            float gs = valid ? (v.x * wg4.x + v.y * wg4.y + v.z * wg4.z + v.w * wg4.w) : 0.f;
            #pragma unroll
            for (int sh = 16; sh > 0; sh >>= 1) gs += __shfl_xor(gs, sh);
            if ((lane & 31) == 0 && valid) efac[n] = __expf(gs + bg0);
        }
    }
    __syncthreads();

    // phase 5: feat (+msg) MFMAs, A from sXn
    bf16x8 a2[4];
    #pragma unroll
    for (int kc = 0; kc < 4; ++kc) {
        const int k = kc * 32 + hi * 8;
        a2[kc] = *reinterpret_cast<const bf16x8*>(&sXn[(rw * 16 + lo) * 136 + k]);
    }
    f32x4 accF[4], accM[4];
    #pragma unroll
    for (int t = 0; t < 4; ++t) { accF[t] = (f32x4){0.f,0.f,0.f,0.f}; accM[t] = (f32x4){0.f,0.f,0.f,0.f}; }
    #pragma unroll
    for (int kc = 0; kc < 4; ++kc) {
        const int k = kc * 32 + hi * 8;
        #pragma unroll
        for (int t = 0; t < 4; ++t) {
            const int o = cw * 64 + t * 16 + lo;
            bf16x8 bv = *reinterpret_cast<const bf16x8*>(&Wf[(size_t)o * 128 + k]);
            accF[t] = __builtin_amdgcn_mfma_f32_16x16x32_bf16(a2[kc], bv, accF[t], 0, 0, 0);
            if (MSG) {
                bf16x8 bv2 = *reinterpret_cast<const bf16x8*>(&Wm2[(size_t)o * 128 + k]);
                accM[t] = __builtin_amdgcn_mfma_f32_16x16x32_bf16(a2[kc], bv2, accM[t], 0, 0, 0);
            }
        }
    }
    __syncthreads();

    // phase 6/7: stage + store feat
    #pragma unroll
    for (int t = 0; t < 4; ++t) {
        const int oc = cw * 64 + t * 16 + lo;
        const int col = oc ^ swz;
        const float bc = bfp[oc];
        #pragma unroll
        for (int r = 0; r < 4; ++r) sY[(lrow + r) * 128 + col] = lk(accF[t][r] + bc);
    }
    __syncthreads();
    #pragma unroll
    for (int it = 0; it < 2; ++it) {
        const int idx = it * 256 + tid;
        const int row = idx >> 4, ub = (idx & 15) * 8;
        const int n = n0 + row;
        if (n < NN) {
            const int ubx = ub ^ (((row >> 2) & 1) << 4);
            bf16x8 ob;
            #pragma unroll
            for (int j = 0; j < 8; ++j) ob[j] = (short)f2b(sY[row * 128 + ubx + j]);
            *reinterpret_cast<bf16x8*>(&featb[(size_t)n * 128 + ub]) = ob;
        }
    }

    if (MSG) {
        __syncthreads();
        #pragma unroll
        for (int t = 0; t < 4; ++t) {
            const int oc = cw * 64 + t * 16 + lo;
            const int col = oc ^ swz;
            const float bc = bm2[oc];
            #pragma unroll
            for (int r = 0; r < 4; ++r) sY[(lrow + r) * 128 + col] = lk(accM[t][r] + bc);
        }
        __syncthreads();
        #pragma unroll
        for (int it = 0; it < 2; ++it) {
            const int idx = it * 256 + tid;
            const int row = idx >> 4, ub = (idx & 15) * 8;
            const int n = n0 + row;
            if (n < NN) {
                const int ubx = ub ^ (((row >> 2) & 1) << 4);
                bf16x8 ob;
                #pragma unroll
                for (int j = 0; j < 8; ++j) ob[j] = (short)f2b(sY[row * 128 + ubx + j]);
                *reinterpret_cast<bf16x8*>(&ybm[(size_t)n * 128 + ub]) = ob;
            }
        }
    }
}

// ---------------- scatter-max via CSR: one wave per node, 8 edges/iter, bf16 ----------------
__global__ __launch_bounds__(256) void k_aggmax(const unsigned short* __restrict__ yb,
                                                const int* __restrict__ off,
                                                const int* __restrict__ csr,
                                                unsigned short* __restrict__ aggb) {
    int gtid = blockIdx.x * blockDim.x + threadIdx.x;
    int node = gtid >> 6;
    if (node >= NN) return;
    int lane = threadIdx.x & 63;
    int slot = lane >> 4, c8 = (lane & 15) * 8;
    int b = off[node], e = off[node + 1];
    int deg = e - b;
    float m[8];
    #pragma unroll
    for (int j = 0; j < 8; ++j) m[j] = -3.4e38f;
    if (deg > 0) {
        int T = (deg + 7) >> 3;
        for (int it = 0; it < T; ++it) {
            int p0 = b + it * 8 + slot;
            int p1 = p0 + 4;
            int i0 = csr[p0 < e ? p0 : b];
            int i1 = csr[p1 < e ? p1 : b];
            bf16x8 v0 = *reinterpret_cast<const bf16x8*>(&yb[(size_t)i0 * 128 + c8]);
            bf16x8 v1 = *reinterpret_cast<const bf16x8*>(&yb[(size_t)i1 * 128 + c8]);
            #pragma unroll
            for (int j = 0; j < 8; ++j) m[j] = fmaxf(m[j], fmaxf(b2f(v0[j]), b2f(v1[j])));
        }
    }
    #pragma unroll
    for (int j = 0; j < 8; ++j) m[j] = fmaxf(m[j], __shfl_xor(m[j], 16));
    #pragma unroll
    for (int j = 0; j < 8; ++j) m[j] = fmaxf(m[j], __shfl_xor(m[j], 32));
    if (slot == 0) {
        bf16x8 o;
        #pragma unroll
        for (int j = 0; j < 8; ++j) o[j] = (deg > 0) ? (short)f2b(m[j]) : (short)0;
        *reinterpret_cast<bf16x8*>(&aggb[(size_t)node * 128 + c8]) = o;
    }
}

// ---------------- xg partial sums (+ efac partial sums), deterministic order ----------------
__global__ __launch_bounds__(128) void k_xgpart(const float* __restrict__ efac,
                                                const unsigned short* __restrict__ featb,
                                                const int* __restrict__ goff,
                                                float* __restrict__ part, float* __restrict__ parte) {
    int g = blockIdx.x >> 6, p = blockIdx.x & 63;
    int d = threadIdx.x;
    int b = goff[g], e = goff[g + 1];
    int len = e - b;
    int chunk = (len + XP - 1) / XP;
    int s0 = b + p * chunk;
    int s1 = min(e, s0 + chunk);
    float acc = 0.f, acce = 0.f;
    #pragma unroll 4
    for (int i = s0; i < s1; ++i) {
        float ev = efac[i];
        acce += ev;
        acc += ev * b2f(featb[(size_t)i * 128 + d]);
    }
    part[((size_t)g * XP + p) * 128 + d] = acc;
    if (d == 0) parte[(size_t)g * XP + p] = acce;
}

// ---------------- global transform (combines efac partials -> denom) ----------------
__global__ __launch_bounds__(128) void k_gtrans(const float* __restrict__ part, const float* __restrict__ parte,
                                                const float* __restrict__ Wt, const float* __restrict__ bt,
                                                float* __restrict__ xglob) {
    __shared__ float cat[256];
    int g = blockIdx.x;
    int o = threadIdx.x;
    float xgv = 0.f, se = 0.f;
    #pragma unroll
    for (int p = 0; p < XP; ++p) {
        xgv += part[((size_t)g * XP + p) * 128 + o];
        se  += parte[(size_t)g * XP + p];
    }
    if (se == 0.f) se = 1.f;
    cat[o] = xgv / se;
    cat[128 + o] = xglob[(size_t)g * 128 + o];
    __syncthreads();
    float accv = bt[o];
    const float4* w4 = reinterpret_cast<const float4*>(&Wt[(size_t)o * 256]);
    #pragma unroll 8
    for (int k4 = 0; k4 < 64; ++k4) {
        float4 wv = w4[k4];
        accv += cat[4 * k4 + 0] * wv.x + cat[4 * k4 + 1] * wv.y + cat[4 * k4 + 2] * wv.z + cat[4 * k4 + 3] * wv.w;
    }
    float outv = lk(accv) + cat[128 + o];
    xglob[(size_t)g * 128 + o] = outv;
}

extern "C" void kernel_launch(void* const* d_in, const int* in_sizes, int n_in,
                              void* d_out, int out_size, void* d_ws, size_t ws_size,
                              hipStream_t stream) {
    const float* x_in  = (const float*)d_in[0];
    const float* xg_in = (const float*)d_in[1];
    const float* Wm = (const float*)d_in[3];
    const float* bm = (const float*)d_in[4];
    const float* Wa = (const float*)d_in[5];
    const float* ba = (const float*)d_in[6];
    const float* Wg = (const float*)d_in[7];
    const float* bg = (const float*)d_in[8];
    const float* Wf = (const float*)d_in[9];
    const float* bf = (const float*)d_in[10];
    const float* Wt = (const float*)d_in[11];
    const float* bt = (const float*)d_in[12];
    const int* eidx  = (const int*)d_in[13];
    const int* batch = (const int*)d_in[14];

    float* xout  = (float*)d_out;                 // [N,128] final x (f32, written by LAST mega)
    float* xglob = xout + (size_t)NN * DD;        // [G,128] evolving x_global

    char* w = (char*)d_ws;
    unsigned short* yb    = (unsigned short*)w; w += (size_t)NN * DD * 2;  // msg bf16
    unsigned short* featb = (unsigned short*)w; w += (size_t)NN * DD * 2;  // feat bf16
    unsigned short* aggb  = (unsigned short*)w; w += (size_t)NN * DD * 2;
    unsigned short* xb    = (unsigned short*)w; w += (size_t)NN * DD * 2;  // bf16 x carry
    unsigned short* Wm_b  = (unsigned short*)w; w += (size_t)STEPS * DD * DD * 2;
    unsigned short* Wa_b  = (unsigned short*)w; w += (size_t)STEPS * DD * 2 * DD * 2;
    unsigned short* Wf_b  = (unsigned short*)w; w += (size_t)STEPS * DD * DD * 2;
    float* efac   = (float*)w; w += (size_t)NN * 4;
    float* part   = (float*)w; w += (size_t)GG * XP * DD * 4;
    float* parte  = (float*)w; w += (size_t)GG * XP * 4;
    int* deg    = (int*)w; w += (size_t)(NN + 1) * 4;
    int* off    = (int*)w; w += (size_t)(NN + 1) * 4;
    int* cursor = (int*)w; w += (size_t)NN * 4;
    int* csr    = (int*)w; w += (size_t)EE * 4;
    int* goff   = (int*)w; w += (size_t)(GG + 1) * 4;
    int* bsum   = (int*)w; w += (size_t)NB * 4;
    int* boff   = (int*)w; w += (size_t)NB * 4;

    const int* srcI = eidx;
    const int* dstI = eidx + EE;

    hipMemcpyAsync(xglob, xg_in, (size_t)GG * DD * 4, hipMemcpyDeviceToDevice, stream);

    // one-time conversions
    k_f2b<<<cdiv(NN * DD / 4, 256), 256, 0, stream>>>(x_in, xb, NN * DD / 4);
    k_wcvt<<<cdiv(WC1 + WC2 + WC3, 256), 256, 0, stream>>>(Wm, Wa, Wf, Wm_b, Wa_b, Wf_b);

    // CSR by dst (once per call; reused across steps)
    hipMemsetAsync(deg, 0, (size_t)NN * 4, stream);
    k_count<<<cdiv(EE, 256), 256, 0, stream>>>(dstI, deg);
    k_scan1<<<NB, 256, 0, stream>>>(deg, off, bsum);
    k_scan2<<<1, 256, 0, stream>>>(bsum, boff, off);
    k_scan3<<<NB, 256, 0, stream>>>(boff, off, cursor);
    k_fill<<<cdiv(EE, 256), 256, 0, stream>>>(srcI, dstI, cursor, csr);
    k_goff<<<cdiv(NN, 256), 256, 0, stream>>>(batch, goff);

    const int gemmGrid = cdiv(NN, 32);            // 1563
    const int aggGrid  = cdiv(NN * 64, 256);      // 12500

    // msg_0 = bf16(leaky(x @ Wm[0]^T + bm[0]))
    k_g128<<<gemmGrid, 256, 0, stream>>>(xb, Wm_b, bm, yb);

    for (int i = 0; i < STEPS; ++i) {
        const float* bai = ba + (size_t)i * DD;
        const unsigned short* Wai = Wa_b + (size_t)i * DD * 2 * DD;
        const float* Wgi = Wg + (size_t)i * DD;
        const float* bgi = bg + (size_t)i;
        const unsigned short* Wfi = Wf_b + (size_t)i * DD * DD;
        const float* bfi = bf + (size_t)i * DD;
        const float* Wti = Wt + (size_t)i * DD * 2 * DD;
        const float* bti = bt + (size_t)i * DD;

        // aggb[n] = max over in-edges of yb[src]
        k_aggmax<<<aggGrid, 256, 0, stream>>>(yb, off, csr, aggb);
        // mega: x_new (xb, or xout f32 on last step), efac=exp(gate), feat -> featb, msg_{i+1} -> yb
        if (i < STEPS - 1) {
            const unsigned short* Wmn = Wm_b + (size_t)(i + 1) * DD * DD;
            const float* bmn = bm + (size_t)(i + 1) * DD;
            k_mega<true, false><<<gemmGrid, 256, 0, stream>>>(
                xb, aggb, Wai, bai, Wgi, bgi, Wfi, bfi, Wmn, bmn,
                nullptr, xb, efac, featb, yb);
        } else {
            k_mega<false, true><<<gemmGrid, 256, 0, stream>>>(
                xb, aggb, Wai, bai, Wgi, bgi, Wfi, bfi, nullptr, nullptr,
                xout, nullptr, efac, featb, nullptr);
        }
        // xg partials (+ efac partials) and global transform
        k_xgpart<<<GG * XP, 128, 0, stream>>>(efac, featb, goff, part, parte);
        k_gtrans<<<GG, 128, 0, stream>>>(part, parte, Wti, bti, xglob);
    }
}